// Round 7
// baseline (157.335 us; speedup 1.0000x reference)
//
#include <hip/hip_runtime.h>
#include <hip/hip_bf16.h>

using f32x4  = __attribute__((ext_vector_type(4))) float;
using bf16x8 = __attribute__((ext_vector_type(8))) short;
using i32x4  = __attribute__((ext_vector_type(4))) int;

static constexpr float SCALE = 0.17677669529663687f; // 32^-0.5
static constexpr float L2E   = 1.4426950408889634f;
static constexpr float SL    = SCALE * L2E;

__device__ inline int cvtpk(float lo, float hi) {
  int r;
  asm("v_cvt_pk_bf16_f32 %0,%1,%2" : "=v"(r) : "v"(lo), "v"(hi));
  return r;
}

// ---- wave+block reduce (sum, sumsq), 256-thread blocks --------------------
__device__ inline void bred2(float& s, float& ss) {
  #pragma unroll
  for (int off = 32; off; off >>= 1) {
    s  += __shfl_down(s, off, 64);
    ss += __shfl_down(ss, off, 64);
  }
  __shared__ float as_[4], ass_[4];
  int wid = threadIdx.x >> 6;
  if ((threadIdx.x & 63) == 0) { as_[wid] = s; ass_[wid] = ss; }
  __syncthreads();
  s  = as_[0] + as_[1] + as_[2] + as_[3];
  ss = ass_[0] + ass_[1] + ass_[2] + ass_[3];
}

// ---- K1: BN stats for x1 and x2 -------------------------------------------
__global__ __launch_bounds__(256) void bnstat_both_kernel(
    const float* __restrict__ x1, const float* __restrict__ x2,
    const float* __restrict__ gl, const float* __restrict__ bl,
    const float* __restrict__ gh, const float* __restrict__ bh,
    float* __restrict__ ab_l, float* __restrict__ ab_h) {
  int b = blockIdx.x;
  const float* src; const float *gamma, *beta; float* ab; int S, C, c;
  if (b < 256) { c = b;       src = x1 + (size_t)c * 512;  S = 512;  C = 256; gamma = gl; beta = bl; ab = ab_l; }
  else         { c = b - 256; src = x2 + (size_t)c * 4096; S = 4096; C = 128; gamma = gh; beta = bh; ab = ab_h; }
  float s = 0.f, ss = 0.f;
  for (int i = threadIdx.x; i < S; i += 256) { float v = src[i]; s += v; ss = fmaf(v, v, ss); }
  bred2(s, ss);
  if (threadIdx.x == 0) {
    float inv = 1.0f / (float)S;
    float m   = s * inv;
    float var = ss * inv - m * m;
    float a   = gamma[c] * rsqrtf(var + 1e-5f);
    ab[c]     = a;
    ab[C + c] = beta[c] - m * a;
  }
}

// ---- depthwise 3x3x3 body -------------------------------------------------
template<bool AFF>
__device__ inline void dw_body(
    const float* __restrict__ in, const float* __restrict__ w,
    const float* __restrict__ ab, float* __restrict__ out,
    int n, int nn, int n3, int C, int t) {
  int c = t / n3, s = t - c * n3;
  int z = s / nn, r = s - z * nn, y = r / n, x = r - y * n;
  const float* src = in + (size_t)c * n3;
  const float* wc  = w + c * 27;
  float a = 1.f, b = 0.f;
  if (AFF) { a = ab[c]; b = ab[C + c]; }
  float acc = 0.f;
  #pragma unroll
  for (int kd = 0; kd < 3; kd++) {
    int zz = z + kd - 1;
    if (zz < 0 || zz >= n) continue;
    #pragma unroll
    for (int kh = 0; kh < 3; kh++) {
      int yy = y + kh - 1;
      if (yy < 0 || yy >= n) continue;
      #pragma unroll
      for (int kw = 0; kw < 3; kw++) {
        int xx = x + kw - 1;
        if (xx < 0 || xx >= n) continue;
        float v = src[(zz * n + yy) * n + xx];
        if (AFF) v = fmaf(v, a, b);
        acc = fmaf(v, wc[kd * 9 + kh * 3 + kw], acc);
      }
    }
  }
  out[t] = acc;
}

// ---- K2: stageA = res8 pointwise | dw_kv | dw_q ---------------------------
__global__ __launch_bounds__(256) void stageA_kernel(
    const float* __restrict__ x1, const float* __restrict__ x2,
    const float* __restrict__ w_ch, const float* __restrict__ b_ch,
    const float* __restrict__ kv_dw, const float* __restrict__ q_dw,
    const float* __restrict__ ab_l, const float* __restrict__ ab_h,
    float* __restrict__ res8, float* __restrict__ kvdw, float* __restrict__ qdw) {
  int b = blockIdx.x;
  if (b < 128) {
    int oc0 = (b >> 1) * 2;
    int s   = (b & 1) * 256 + threadIdx.x;
    float a0 = 0.f, a1 = 0.f;
    const float* w0 = w_ch + (size_t)oc0 * 256;
    const float* w1 = w0 + 256;
    #pragma unroll 8
    for (int ic = 0; ic < 256; ic++) {
      float x = x1[(size_t)ic * 512 + s];
      a0 = fmaf(w0[ic], x, a0);
      a1 = fmaf(w1[ic], x, a1);
    }
    res8[(size_t)oc0 * 512 + s]       = a0 + b_ch[oc0];
    res8[(size_t)(oc0 + 1) * 512 + s] = a1 + b_ch[oc0 + 1];
  } else if (b < 640) {
    dw_body<true>(x1, kv_dw, ab_l, kvdw, 8, 64, 512, 256, (b - 128) * 256 + threadIdx.x);
  } else {
    dw_body<true>(x2, q_dw, ab_h, qdw, 16, 256, 4096, 128, (b - 640) * 256 + threadIdx.x);
  }
}

// ---- trilinear helpers ----------------------------------------------------
__device__ inline void icoef8(int o, int& lo, int& hi, float& w) {
  float p = (float)o * (7.0f / 15.0f);
  int l = (int)floorf(p);
  if (l > 7) l = 7;
  int h = l + 1 > 7 ? 7 : l + 1;
  w  = p - (float)l;
  lo = l; hi = h;
}

__device__ inline float trilin8(const float* __restrict__ p,
                                int z0, int z1, float wz,
                                int y0, int y1, float wy,
                                int x0, int x1, float wx) {
  float c00 = p[(z0*8+y0)*8+x0]*(1.f-wx) + p[(z0*8+y0)*8+x1]*wx;
  float c01 = p[(z0*8+y1)*8+x0]*(1.f-wx) + p[(z0*8+y1)*8+x1]*wx;
  float c10 = p[(z1*8+y0)*8+x0]*(1.f-wx) + p[(z1*8+y0)*8+x1]*wx;
  float c11 = p[(z1*8+y1)*8+x0]*(1.f-wx) + p[(z1*8+y1)*8+x1]*wx;
  float c0 = c00*(1.f-wy) + c01*wy;
  float c1 = c10*(1.f-wy) + c11*wy;
  return c0*(1.f-wz) + c1*wz;
}

// ---- K3: stageB = pw_kv+interp->Kb/Vt | pw_q->Qpk | interp_res ------------
__global__ __launch_bounds__(512) void stageB_kernel(
    const float* __restrict__ kvdw, const float* __restrict__ kv_pw,
    const float* __restrict__ qdw, const float* __restrict__ q_pw,
    const float* __restrict__ res8,
    unsigned short* __restrict__ Kb, unsigned short* __restrict__ Vt,
    unsigned short* __restrict__ Qpk, float* __restrict__ r16) {
  __shared__ float sm[2][512];
  int b = blockIdx.x;
  int tid = threadIdx.x;
  if (b < 128) {
    int kc0 = b * 2;
    int s = tid;
    float a0 = 0.f, a1 = 0.f;
    const float* w0 = kv_pw + (size_t)kc0 * 256;
    const float* w1 = w0 + 256;
    #pragma unroll 8
    for (int ic = 0; ic < 256; ic++) {
      float x = kvdw[(size_t)ic * 512 + s];
      a0 = fmaf(w0[ic], x, a0);
      a1 = fmaf(w1[ic], x, a1);
    }
    sm[0][s] = a0; sm[1][s] = a1;
    __syncthreads();
    #pragma unroll
    for (int r = 0; r < 16; r++) {
      int u  = r * 512 + tid;
      int cl = u >> 12, j = u & 4095;
      int z = j >> 8, y = (j >> 4) & 15, x = j & 15;
      int z0,z1,y0,y1,x0,x1; float wz,wy,wx;
      icoef8(z, z0, z1, wz); icoef8(y, y0, y1, wy); icoef8(x, x0, x1, wx);
      float val = trilin8(sm[cl], z0, z1, wz, y0, y1, wy, x0, x1, wx);
      __hip_bfloat16 bv = __float2bfloat16(val);
      unsigned short us = *reinterpret_cast<unsigned short*>(&bv);
      int kc = kc0 + cl;
      int c  = kc & 127;
      int head = c & 3, dh = c >> 2;
      if (kc < 128) Kb[((size_t)(head << 12) + j) * 32 + dh] = us;
      else          Vt[((size_t)(head * 32) + dh) * 4096 + j] = us;
    }
  } else if (b < 256) {
    int bb   = b - 128;
    int head = bb >> 5;
    int r2   = bb & 31;
    int dh0  = (r2 >> 3) * 8;
    int i    = (r2 & 7) * 512 + tid;
    float acc[8];
    #pragma unroll
    for (int e = 0; e < 8; e++) acc[e] = 0.f;
    #pragma unroll 4
    for (int ic = 0; ic < 128; ic++) {
      float x = qdw[(size_t)ic * 4096 + i];
      #pragma unroll
      for (int e = 0; e < 8; e++)
        acc[e] = fmaf(q_pw[(size_t)((dh0 + e) * 4 + head) * 128 + ic], x, acc[e]);
    }
    i32x4 pk = { cvtpk(acc[0], acc[1]), cvtpk(acc[2], acc[3]),
                 cvtpk(acc[4], acc[5]), cvtpk(acc[6], acc[7]) };
    *reinterpret_cast<i32x4*>(Qpk + ((size_t)(head << 12) + i) * 32 + dh0) = pk;
  } else {
    int t = (b - 256) * 512 + tid;   // 524288
    int s = t & 4095, c = t >> 12;
    int z = s >> 8, y = (s >> 4) & 15, x = s & 15;
    int z0,z1,y0,y1,x0,x1; float wz,wy,wx;
    icoef8(z, z0, z1, wz); icoef8(y, y0, y1, wy); icoef8(x, x0, x1, wx);
    r16[t] = trilin8(res8 + c * 512, z0, z1, wz, y0, y1, wy, x0, x1, wx);
  }
}

// ---- K4: MFMA flash attention, in-block K-split x8 (8 waves, 512 thr) -----
// grid 1024 (4 heads x 256 strips) x 8 waves -> 32 waves/CU (full occupancy).
// Each wave: 16 queries x 512 keys (16 iterations of 32).
__global__ __launch_bounds__(512, 8) void attn_mfma_kernel(
    const unsigned short* __restrict__ Qpk, const unsigned short* __restrict__ Kb,
    const unsigned short* __restrict__ Vt, const float* __restrict__ table,
    float* __restrict__ o_sp) {
  __shared__ float lut[992];
  __shared__ float red_o[8 * 64 * 9];   // [wave][lane][8] pad 9
  __shared__ float red_ml[2][8][16];
  int head  = blockIdx.x >> 8;
  int strip = blockIdx.x & 255;
  for (int u = threadIdx.x; u < 991; u += 512) {
    int p = (u < 15) ? (u - 15 + 29791) : (u - 15);
    lut[u] = table[p * 4 + head] * SL;
  }
  __syncthreads();

  int w    = threadIdx.x >> 6;
  int lane = threadIdx.x & 63;
  int qrow = lane & 15;
  int g    = lane >> 4;
  int i    = strip * 16 + qrow;
  int iz = i >> 8, iy = (i >> 4) & 15, ix = i & 15;
  int lanebase = iz * 31 + iy + ix;

  bf16x8 qf = *(const bf16x8*)(Qpk + ((size_t)(head << 12) + i) * 32 + g * 8);

  const unsigned short* Kh = Kb + (size_t)head * 4096 * 32;
  const unsigned short* Vh = Vt + (size_t)head * 32 * 4096;

  f32x4 zero = {0.f, 0.f, 0.f, 0.f};
  f32x4 accO0 = zero, accO1 = zero;
  float m2 = -1e30f, lpart = 0.f;

  int kt0 = w * 16;                     // wave's 512-key range: tiles kt0..kt0+15
  bf16x8 kf0 = *(const bf16x8*)(Kh + ((size_t)(kt0 * 32 + qrow)) * 32 + g * 8);
  bf16x8 kf1 = *(const bf16x8*)(Kh + ((size_t)(kt0 * 32 + 16 + qrow)) * 32 + g * 8);
  bf16x8 vf0 = *(const bf16x8*)(Vh + (size_t)(qrow)  * 4096 + kt0 * 32 + g * 8);
  bf16x8 vf1 = *(const bf16x8*)(Vh + (size_t)(16 + qrow) * 4096 + kt0 * 32 + g * 8);

  for (int ktl = 0; ktl < 16; ktl++) {
    int kt  = kt0 + ktl;
    int nkt = kt0 + ((ktl + 1) & 15);
    bf16x8 nk0 = *(const bf16x8*)(Kh + ((size_t)(nkt * 32 + qrow)) * 32 + g * 8);
    bf16x8 nk1 = *(const bf16x8*)(Kh + ((size_t)(nkt * 32 + 16 + qrow)) * 32 + g * 8);
    bf16x8 nv0 = *(const bf16x8*)(Vh + (size_t)(qrow)  * 4096 + nkt * 32 + g * 8);
    bf16x8 nv1 = *(const bf16x8*)(Vh + (size_t)(16 + qrow) * 4096 + nkt * 32 + g * 8);

    f32x4 accA = __builtin_amdgcn_mfma_f32_16x16x32_bf16(kf0, qf, zero, 0, 0, 0);
    f32x4 accB = __builtin_amdgcn_mfma_f32_16x16x32_bf16(kf1, qf, zero, 0, 0, 0);

    int z0 = kt >> 3, y0 = (kt << 1) & 15;
    int Cc = 495 - 31 * z0 - y0;
    const float* lp = &lut[lanebase + Cc - 4 * g - 4];
    float l0 = lp[0], l1 = lp[1], l2 = lp[2], l3 = lp[3], l4 = lp[4];

    float t0 = fmaf(accA[0], SL, l4);
    float t1 = fmaf(accA[1], SL, l3);
    float t2 = fmaf(accA[2], SL, l2);
    float t3 = fmaf(accA[3], SL, l1);
    float t4 = fmaf(accB[0], SL, l3);
    float t5 = fmaf(accB[1], SL, l2);
    float t6 = fmaf(accB[2], SL, l1);
    float t7 = fmaf(accB[3], SL, l0);

    float cm = fmaxf(fmaxf(fmaxf(t0, t1), fmaxf(t2, t3)),
                     fmaxf(fmaxf(t4, t5), fmaxf(t6, t7)));
    cm = fmaxf(cm, __shfl_xor(cm, 16, 64));
    cm = fmaxf(cm, __shfl_xor(cm, 32, 64));

    if (__any(cm > m2 + 8.f)) {
      float mn   = fmaxf(m2, cm);
      float corr = exp2f(m2 - mn);
      m2 = mn;
      lpart *= corr;
      accO0[0] *= corr; accO0[1] *= corr; accO0[2] *= corr; accO0[3] *= corr;
      accO1[0] *= corr; accO1[1] *= corr; accO1[2] *= corr; accO1[3] *= corr;
    }

    float p0 = exp2f(t0 - m2), p1 = exp2f(t1 - m2);
    float p2 = exp2f(t2 - m2), p3 = exp2f(t3 - m2);
    float p4 = exp2f(t4 - m2), p5 = exp2f(t5 - m2);
    float p6 = exp2f(t6 - m2), p7 = exp2f(t7 - m2);
    lpart += ((p0 + p1) + (p2 + p3)) + ((p4 + p5) + (p6 + p7));

    int w0 = cvtpk(p0, p1), w1 = cvtpk(p2, p3);
    int w2 = cvtpk(p4, p5), w3 = cvtpk(p6, p7);
    int srcA = ((g & 1) << 5) + qrow;
    int srcB = srcA + 16;
    int x0 = __shfl(w0, srcA, 64), x1 = __shfl(w1, srcA, 64);
    int x2 = __shfl(w2, srcA, 64), x3 = __shfl(w3, srcA, 64);
    int y0s = __shfl(w0, srcB, 64), y1s = __shfl(w1, srcB, 64);
    int y2s = __shfl(w2, srcB, 64), y3s = __shfl(w3, srcB, 64);
    bool thi = (g >> 1) != 0;
    union { i32x4 i4; bf16x8 s8; } up;
    up.i4 = (i32x4){ thi ? x2 : x0, thi ? x3 : x1,
                     thi ? y2s : y0s, thi ? y3s : y1s };

    accO0 = __builtin_amdgcn_mfma_f32_16x16x32_bf16(vf0, up.s8, accO0, 0, 0, 0);
    accO1 = __builtin_amdgcn_mfma_f32_16x16x32_bf16(vf1, up.s8, accO1, 0, 0, 0);

    kf0 = nk0; kf1 = nk1; vf0 = nv0; vf1 = nv1;
  }

  float lsum = lpart + __shfl_xor(lpart, 16, 64);
  lsum += __shfl_xor(lsum, 32, 64);

  int lbase = (w * 64 + lane) * 9;
  #pragma unroll
  for (int r = 0; r < 4; r++) { red_o[lbase + r] = accO0[r]; red_o[lbase + 4 + r] = accO1[r]; }
  if (g == 0) { red_ml[0][w][qrow] = m2; red_ml[1][w][qrow] = lsum; }
  __syncthreads();

  if (w == 0) {
    float ml[8];
    float mx = -1e30f;
    #pragma unroll
    for (int wv = 0; wv < 8; wv++) { ml[wv] = red_ml[0][wv][qrow]; mx = fmaxf(mx, ml[wv]); }
    float c[8];
    float L = 0.f;
    #pragma unroll
    for (int wv = 0; wv < 8; wv++) {
      c[wv] = exp2f(ml[wv] - mx);
      L = fmaf(c[wv], red_ml[1][wv][qrow], L);
    }
    float inv = 1.0f / L;
    #pragma unroll
    for (int r = 0; r < 8; r++) {
      float o = 0.f;
      #pragma unroll
      for (int wv = 0; wv < 8; wv++)
        o = fmaf(c[wv], red_o[(wv * 64 + lane) * 9 + r], o);
      int d0 = (r < 4) ? (4 * g + r) : (16 + 4 * g + (r - 4));
      o_sp[(size_t)(d0 * 4 + head) * 4096 + i] = o * inv;
    }
  }
}

// ---- K5: depthwise out projection ----------------------------------------
__global__ __launch_bounds__(256) void dw_out_kernel(
    const float* __restrict__ in, const float* __restrict__ w, float* __restrict__ out) {
  dw_body<false>(in, w, nullptr, out, 16, 256, 4096, 128, blockIdx.x * 256 + threadIdx.x);
}

// ---- K6: pw_out 128->128 + r16 residue + deterministic BN partial sums ----
__global__ __launch_bounds__(256) void pw_out_kernel(
    const float* __restrict__ in, const float* __restrict__ w,
    const float* __restrict__ r16, float* __restrict__ res2,
    float* __restrict__ sums) {
  __shared__ float red[4][2][2];
  int oc0 = (blockIdx.x >> 3) * 2;
  int sb  = blockIdx.x & 7;
  int s0  = (sb * 256 + threadIdx.x) * 2;
  float a00 = 0.f, a01 = 0.f, a10 = 0.f, a11 = 0.f;
  const float* w0 = w + (size_t)oc0 * 128;
  const float* w1 = w0 + 128;
  #pragma unroll 8
  for (int ic = 0; ic < 128; ic++) {
    float xa = in[(size_t)ic * 4096 + s0];
    float xb = in[(size_t)ic * 4096 + s0 + 1];
    float wv0 = w0[ic], wv1 = w1[ic];
    a00 = fmaf(wv0, xa, a00); a01 = fmaf(wv0, xb, a01);
    a10 = fmaf(wv1, xa, a10); a11 = fmaf(wv1, xb, a11);
  }
  size_t ob0 = (size_t)oc0 * 4096 + s0;
  size_t ob1 = ob0 + 4096;
  float r00 = a00 + r16[ob0],     r01 = a01 + r16[ob0 + 1];
  float r10 = a10 + r16[ob1],     r11 = a11 + r16[ob1 + 1];
  res2[ob0] = r00; res2[ob0 + 1] = r01;
  res2[ob1] = r10; res2[ob1 + 1] = r11;
  float s_0 = r00 + r01, q_0 = fmaf(r00, r00, r01 * r01);
  float s_1 = r10 + r11, q_1 = fmaf(r10, r10, r11 * r11);
  #pragma unroll
  for (int off = 32; off; off >>= 1) {
    s_0 += __shfl_down(s_0, off, 64); q_0 += __shfl_down(q_0, off, 64);
    s_1 += __shfl_down(s_1, off, 64); q_1 += __shfl_down(q_1, off, 64);
  }
  int wid = threadIdx.x >> 6;
  if ((threadIdx.x & 63) == 0) {
    red[wid][0][0] = s_0; red[wid][0][1] = q_0;
    red[wid][1][0] = s_1; red[wid][1][1] = q_1;
  }
  __syncthreads();
  if (threadIdx.x < 2) {
    int o = threadIdx.x;
    float st = red[0][o][0] + red[1][o][0] + red[2][o][0] + red[3][o][0];
    float qt = red[0][o][1] + red[1][o][1] + red[2][o][1] + red[3][o][1];
    sums[(oc0 + o) * 8 + sb]        = st;
    sums[1024 + (oc0 + o) * 8 + sb] = qt;
  }
}

// ---- K7: mlp pw with in-block BN-affine finalize + ReLU + residual --------
__global__ __launch_bounds__(256) void pw_mlp_kernel(
    const float* __restrict__ res2, const float* __restrict__ w,
    const float* __restrict__ gamma2, const float* __restrict__ beta2,
    const float* __restrict__ sums, float* __restrict__ out) {
  __shared__ float A[128], Bb[128];
  if (threadIdx.x < 128) {
    int c = threadIdx.x;
    float s = 0.f, q = 0.f;
    #pragma unroll
    for (int sb = 0; sb < 8; sb++) { s += sums[c * 8 + sb]; q += sums[1024 + c * 8 + sb]; }
    float m   = s * (1.0f / 4096.0f);
    float var = q * (1.0f / 4096.0f) - m * m;
    float a   = gamma2[c] * rsqrtf(var + 1e-5f);
    A[c]  = a;
    Bb[c] = beta2[c] - m * a;
  }
  __syncthreads();
  int oc0 = (blockIdx.x >> 3) * 2;
  int sb  = blockIdx.x & 7;
  int s0  = (sb * 256 + threadIdx.x) * 2;
  float a00 = 0.f, a01 = 0.f, a10 = 0.f, a11 = 0.f;
  const float* w0 = w + (size_t)oc0 * 128;
  const float* w1 = w0 + 128;
  #pragma unroll 8
  for (int ic = 0; ic < 128; ic++) {
    float aa = A[ic], bb = Bb[ic];
    float xa = fmaxf(fmaf(res2[(size_t)ic * 4096 + s0], aa, bb), 0.f);
    float xb = fmaxf(fmaf(res2[(size_t)ic * 4096 + s0 + 1], aa, bb), 0.f);
    float wv0 = w0[ic], wv1 = w1[ic];
    a00 = fmaf(wv0, xa, a00); a01 = fmaf(wv0, xb, a01);
    a10 = fmaf(wv1, xa, a10); a11 = fmaf(wv1, xb, a11);
  }
  size_t ob0 = (size_t)oc0 * 4096 + s0;
  size_t ob1 = ob0 + 4096;
  out[ob0]     = a00 + res2[ob0];
  out[ob0 + 1] = a01 + res2[ob0 + 1];
  out[ob1]     = a10 + res2[ob1];
  out[ob1 + 1] = a11 + res2[ob1 + 1];
}

// ---------------------------------------------------------------------------
extern "C" void kernel_launch(void* const* d_in, const int* in_sizes, int n_in,
                              void* d_out, int out_size, void* d_ws, size_t ws_size,
                              hipStream_t stream) {
  (void)in_sizes; (void)n_in; (void)out_size; (void)ws_size;
  const float* x1      = (const float*)d_in[0];
  const float* x2      = (const float*)d_in[1];
  const float* w_ch    = (const float*)d_in[2];
  const float* b_ch    = (const float*)d_in[3];
  const float* gamma_l = (const float*)d_in[4];
  const float* beta_l  = (const float*)d_in[5];
  const float* gamma_h = (const float*)d_in[6];
  const float* beta_h  = (const float*)d_in[7];
  const float* gamma2  = (const float*)d_in[8];
  const float* beta2   = (const float*)d_in[9];
  const float* kv_dw   = (const float*)d_in[10];
  const float* kv_pw   = (const float*)d_in[11];
  const float* q_dw    = (const float*)d_in[12];
  const float* q_pw    = (const float*)d_in[13];
  const float* out_dw  = (const float*)d_in[14];
  const float* out_pw  = (const float*)d_in[15];
  const float* w_mlp   = (const float*)d_in[16];
  const float* rtab    = (const float*)d_in[17];

  float* ws = (float*)d_ws;
  // sizes in FLOATS. Qpk/Kb/Vt each hold 4*4096*32 = 524288 bf16 = 262144 floats.
  float* ab_l = ws + 0;        //    512
  float* ab_h = ws + 512;      //    256
  float* sums = ws + 768;      //   2048
  float* res8 = ws + 2816;     //  65536
  float* kvdw = ws + 68352;    // 131072
  float* qdw  = ws + 199424;   // 524288 -> 723712
  unsigned short* Qpk = (unsigned short*)(ws + 723712);   // 262144 f -> 985856
  unsigned short* Kb  = (unsigned short*)(ws + 985856);   // 262144 f -> 1248000
  unsigned short* Vt  = (unsigned short*)(ws + 1248000);  // 262144 f -> 1510144
  float* r16  = ws + 1510144;  // 524288 -> 2034432
  float* o_sp = ws + 2034432;  // 524288 -> 2558720
  float* odw  = ws + 2558720;  // 524288 -> 3083008
  float* res2 = ws + 3083008;  // 524288 -> 3607296 floats (~14.4 MB)

  bnstat_both_kernel<<<384, 256, 0, stream>>>(x1, x2, gamma_l, beta_l, gamma_h, beta_h,
                                              ab_l, ab_h);
  stageA_kernel<<<2688, 256, 0, stream>>>(x1, x2, w_ch, b_ch, kv_dw, q_dw,
                                          ab_l, ab_h, res8, kvdw, qdw);
  stageB_kernel<<<1280, 512, 0, stream>>>(kvdw, kv_pw, qdw, q_pw, res8,
                                          Kb, Vt, Qpk, r16);
  attn_mfma_kernel<<<1024, 512, 0, stream>>>(Qpk, Kb, Vt, rtab, o_sp);
  dw_out_kernel<<<2048, 256, 0, stream>>>(o_sp, out_dw, odw);
  pw_out_kernel<<<512, 256, 0, stream>>>(odw, out_pw, r16, res2, sums);
  pw_mlp_kernel<<<512, 256, 0, stream>>>(res2, w_mlp, gamma2, beta2, sums, (float*)d_out);
}

// Round 8
// 122.195 us; speedup vs baseline: 1.2876x; 1.2876x over previous
//
#include <hip/hip_runtime.h>
#include <hip/hip_bf16.h>

using f32x4  = __attribute__((ext_vector_type(4))) float;
using bf16x8 = __attribute__((ext_vector_type(8))) short;
using i32x4  = __attribute__((ext_vector_type(4))) int;

static constexpr float SCALE = 0.17677669529663687f; // 32^-0.5
static constexpr float L2E   = 1.4426950408889634f;
static constexpr float SL    = SCALE * L2E;

__device__ inline int cvtpk(float lo, float hi) {
  int r;
  asm("v_cvt_pk_bf16_f32 %0,%1,%2" : "=v"(r) : "v"(lo), "v"(hi));
  return r;
}

// ---- wave+block reduce (sum, sumsq), 256-thread blocks --------------------
__device__ inline void bred2(float& s, float& ss) {
  #pragma unroll
  for (int off = 32; off; off >>= 1) {
    s  += __shfl_down(s, off, 64);
    ss += __shfl_down(ss, off, 64);
  }
  __shared__ float as_[4], ass_[4];
  int wid = threadIdx.x >> 6;
  if ((threadIdx.x & 63) == 0) { as_[wid] = s; ass_[wid] = ss; }
  __syncthreads();
  s  = as_[0] + as_[1] + as_[2] + as_[3];
  ss = ass_[0] + ass_[1] + ass_[2] + ass_[3];
}

// ---- K1: BN stats for x1 and x2 -------------------------------------------
__global__ __launch_bounds__(256) void bnstat_both_kernel(
    const float* __restrict__ x1, const float* __restrict__ x2,
    const float* __restrict__ gl, const float* __restrict__ bl,
    const float* __restrict__ gh, const float* __restrict__ bh,
    float* __restrict__ ab_l, float* __restrict__ ab_h) {
  int b = blockIdx.x;
  const float* src; const float *gamma, *beta; float* ab; int S, C, c;
  if (b < 256) { c = b;       src = x1 + (size_t)c * 512;  S = 512;  C = 256; gamma = gl; beta = bl; ab = ab_l; }
  else         { c = b - 256; src = x2 + (size_t)c * 4096; S = 4096; C = 128; gamma = gh; beta = bh; ab = ab_h; }
  float s = 0.f, ss = 0.f;
  for (int i = threadIdx.x; i < S; i += 256) { float v = src[i]; s += v; ss = fmaf(v, v, ss); }
  bred2(s, ss);
  if (threadIdx.x == 0) {
    float inv = 1.0f / (float)S;
    float m   = s * inv;
    float var = ss * inv - m * m;
    float a   = gamma[c] * rsqrtf(var + 1e-5f);
    ab[c]     = a;
    ab[C + c] = beta[c] - m * a;
  }
}

// ---- depthwise 3x3x3 body -------------------------------------------------
template<bool AFF>
__device__ inline void dw_body(
    const float* __restrict__ in, const float* __restrict__ w,
    const float* __restrict__ ab, float* __restrict__ out,
    int n, int nn, int n3, int C, int t) {
  int c = t / n3, s = t - c * n3;
  int z = s / nn, r = s - z * nn, y = r / n, x = r - y * n;
  const float* src = in + (size_t)c * n3;
  const float* wc  = w + c * 27;
  float a = 1.f, b = 0.f;
  if (AFF) { a = ab[c]; b = ab[C + c]; }
  float acc = 0.f;
  #pragma unroll
  for (int kd = 0; kd < 3; kd++) {
    int zz = z + kd - 1;
    if (zz < 0 || zz >= n) continue;
    #pragma unroll
    for (int kh = 0; kh < 3; kh++) {
      int yy = y + kh - 1;
      if (yy < 0 || yy >= n) continue;
      #pragma unroll
      for (int kw = 0; kw < 3; kw++) {
        int xx = x + kw - 1;
        if (xx < 0 || xx >= n) continue;
        float v = src[(zz * n + yy) * n + xx];
        if (AFF) v = fmaf(v, a, b);
        acc = fmaf(v, wc[kd * 9 + kh * 3 + kw], acc);
      }
    }
  }
  out[t] = acc;
}

// ---- K2: stageA = res8 pointwise | dw_kv | dw_q ---------------------------
__global__ __launch_bounds__(256) void stageA_kernel(
    const float* __restrict__ x1, const float* __restrict__ x2,
    const float* __restrict__ w_ch, const float* __restrict__ b_ch,
    const float* __restrict__ kv_dw, const float* __restrict__ q_dw,
    const float* __restrict__ ab_l, const float* __restrict__ ab_h,
    float* __restrict__ res8, float* __restrict__ kvdw, float* __restrict__ qdw) {
  int b = blockIdx.x;
  if (b < 128) {
    int oc0 = (b >> 1) * 2;
    int s   = (b & 1) * 256 + threadIdx.x;
    float a0 = 0.f, a1 = 0.f;
    const float* w0 = w_ch + (size_t)oc0 * 256;
    const float* w1 = w0 + 256;
    #pragma unroll 8
    for (int ic = 0; ic < 256; ic++) {
      float x = x1[(size_t)ic * 512 + s];
      a0 = fmaf(w0[ic], x, a0);
      a1 = fmaf(w1[ic], x, a1);
    }
    res8[(size_t)oc0 * 512 + s]       = a0 + b_ch[oc0];
    res8[(size_t)(oc0 + 1) * 512 + s] = a1 + b_ch[oc0 + 1];
  } else if (b < 640) {
    dw_body<true>(x1, kv_dw, ab_l, kvdw, 8, 64, 512, 256, (b - 128) * 256 + threadIdx.x);
  } else {
    dw_body<true>(x2, q_dw, ab_h, qdw, 16, 256, 4096, 128, (b - 640) * 256 + threadIdx.x);
  }
}

// ---- trilinear helpers ----------------------------------------------------
__device__ inline void icoef8(int o, int& lo, int& hi, float& w) {
  float p = (float)o * (7.0f / 15.0f);
  int l = (int)floorf(p);
  if (l > 7) l = 7;
  int h = l + 1 > 7 ? 7 : l + 1;
  w  = p - (float)l;
  lo = l; hi = h;
}

__device__ inline float trilin8(const float* __restrict__ p,
                                int z0, int z1, float wz,
                                int y0, int y1, float wy,
                                int x0, int x1, float wx) {
  float c00 = p[(z0*8+y0)*8+x0]*(1.f-wx) + p[(z0*8+y0)*8+x1]*wx;
  float c01 = p[(z0*8+y1)*8+x0]*(1.f-wx) + p[(z0*8+y1)*8+x1]*wx;
  float c10 = p[(z1*8+y0)*8+x0]*(1.f-wx) + p[(z1*8+y0)*8+x1]*wx;
  float c11 = p[(z1*8+y1)*8+x0]*(1.f-wx) + p[(z1*8+y1)*8+x1]*wx;
  float c0 = c00*(1.f-wy) + c01*wy;
  float c1 = c10*(1.f-wy) + c11*wy;
  return c0*(1.f-wz) + c1*wz;
}

// ---- K3: stageB = pw_kv+interp->Kb/Vt | pw_q->Qpk | interp_res ------------
__global__ __launch_bounds__(512) void stageB_kernel(
    const float* __restrict__ kvdw, const float* __restrict__ kv_pw,
    const float* __restrict__ qdw, const float* __restrict__ q_pw,
    const float* __restrict__ res8,
    unsigned short* __restrict__ Kb, unsigned short* __restrict__ Vt,
    unsigned short* __restrict__ Qpk, float* __restrict__ r16) {
  __shared__ float sm[2][512];
  int b = blockIdx.x;
  int tid = threadIdx.x;
  if (b < 128) {
    int kc0 = b * 2;
    int s = tid;
    float a0 = 0.f, a1 = 0.f;
    const float* w0 = kv_pw + (size_t)kc0 * 256;
    const float* w1 = w0 + 256;
    #pragma unroll 8
    for (int ic = 0; ic < 256; ic++) {
      float x = kvdw[(size_t)ic * 512 + s];
      a0 = fmaf(w0[ic], x, a0);
      a1 = fmaf(w1[ic], x, a1);
    }
    sm[0][s] = a0; sm[1][s] = a1;
    __syncthreads();
    #pragma unroll
    for (int r = 0; r < 16; r++) {
      int u  = r * 512 + tid;
      int cl = u >> 12, j = u & 4095;
      int z = j >> 8, y = (j >> 4) & 15, x = j & 15;
      int z0,z1,y0,y1,x0,x1; float wz,wy,wx;
      icoef8(z, z0, z1, wz); icoef8(y, y0, y1, wy); icoef8(x, x0, x1, wx);
      float val = trilin8(sm[cl], z0, z1, wz, y0, y1, wy, x0, x1, wx);
      __hip_bfloat16 bv = __float2bfloat16(val);
      unsigned short us = *reinterpret_cast<unsigned short*>(&bv);
      int kc = kc0 + cl;
      int c  = kc & 127;
      int head = c & 3, dh = c >> 2;
      if (kc < 128) Kb[((size_t)(head << 12) + j) * 32 + dh] = us;
      else          Vt[((size_t)(head * 32) + dh) * 4096 + j] = us;
    }
  } else if (b < 256) {
    int bb   = b - 128;
    int head = bb >> 5;
    int r2   = bb & 31;
    int dh0  = (r2 >> 3) * 8;
    int i    = (r2 & 7) * 512 + tid;
    float acc[8];
    #pragma unroll
    for (int e = 0; e < 8; e++) acc[e] = 0.f;
    #pragma unroll 4
    for (int ic = 0; ic < 128; ic++) {
      float x = qdw[(size_t)ic * 4096 + i];
      #pragma unroll
      for (int e = 0; e < 8; e++)
        acc[e] = fmaf(q_pw[(size_t)((dh0 + e) * 4 + head) * 128 + ic], x, acc[e]);
    }
    i32x4 pk = { cvtpk(acc[0], acc[1]), cvtpk(acc[2], acc[3]),
                 cvtpk(acc[4], acc[5]), cvtpk(acc[6], acc[7]) };
    *reinterpret_cast<i32x4*>(Qpk + ((size_t)(head << 12) + i) * 32 + dh0) = pk;
  } else {
    int t = (b - 256) * 512 + tid;   // 524288
    int s = t & 4095, c = t >> 12;
    int z = s >> 8, y = (s >> 4) & 15, x = s & 15;
    int z0,z1,y0,y1,x0,x1; float wz,wy,wx;
    icoef8(z, z0, z1, wz); icoef8(y, y0, y1, wy); icoef8(x, x0, x1, wx);
    r16[t] = trilin8(res8 + c * 512, z0, z1, wz, y0, y1, wy, x0, x1, wx);
  }
}

// ---- K4: MFMA flash attention, in-block K-split x8 (8 waves, 512 thr) -----
// grid 1024 (4 heads x 256 strips) x 8 waves. __launch_bounds__(512,4):
// 128-VGPR budget (no spill; kernel needs ~40-48). At ~48 VGPR, 8 waves/SIMD
// still fit naturally -> up to 32 waves/CU without forcing the allocator.
__global__ __launch_bounds__(512, 4) void attn_mfma_kernel(
    const unsigned short* __restrict__ Qpk, const unsigned short* __restrict__ Kb,
    const unsigned short* __restrict__ Vt, const float* __restrict__ table,
    float* __restrict__ o_sp) {
  __shared__ float lut[992];
  __shared__ float red_o[8 * 64 * 9];   // [wave][lane][8] pad 9
  __shared__ float red_ml[2][8][16];
  int head  = blockIdx.x >> 8;
  int strip = blockIdx.x & 255;
  for (int u = threadIdx.x; u < 991; u += 512) {
    int p = (u < 15) ? (u - 15 + 29791) : (u - 15);
    lut[u] = table[p * 4 + head] * SL;
  }
  __syncthreads();

  int w    = threadIdx.x >> 6;
  int lane = threadIdx.x & 63;
  int qrow = lane & 15;
  int g    = lane >> 4;
  int i    = strip * 16 + qrow;
  int iz = i >> 8, iy = (i >> 4) & 15, ix = i & 15;
  int lanebase = iz * 31 + iy + ix;

  bf16x8 qf = *(const bf16x8*)(Qpk + ((size_t)(head << 12) + i) * 32 + g * 8);

  const unsigned short* Kh = Kb + (size_t)head * 4096 * 32;
  const unsigned short* Vh = Vt + (size_t)head * 32 * 4096;

  f32x4 zero = {0.f, 0.f, 0.f, 0.f};
  f32x4 accO0 = zero, accO1 = zero;
  float m2 = -1e30f, lpart = 0.f;

  int kt0 = w * 16;                     // wave's 512-key range: tiles kt0..kt0+15
  bf16x8 kf0 = *(const bf16x8*)(Kh + ((size_t)(kt0 * 32 + qrow)) * 32 + g * 8);
  bf16x8 kf1 = *(const bf16x8*)(Kh + ((size_t)(kt0 * 32 + 16 + qrow)) * 32 + g * 8);
  bf16x8 vf0 = *(const bf16x8*)(Vh + (size_t)(qrow)  * 4096 + kt0 * 32 + g * 8);
  bf16x8 vf1 = *(const bf16x8*)(Vh + (size_t)(16 + qrow) * 4096 + kt0 * 32 + g * 8);

  for (int ktl = 0; ktl < 16; ktl++) {
    int kt  = kt0 + ktl;
    int nkt = kt0 + ((ktl + 1) & 15);
    bf16x8 nk0 = *(const bf16x8*)(Kh + ((size_t)(nkt * 32 + qrow)) * 32 + g * 8);
    bf16x8 nk1 = *(const bf16x8*)(Kh + ((size_t)(nkt * 32 + 16 + qrow)) * 32 + g * 8);
    bf16x8 nv0 = *(const bf16x8*)(Vh + (size_t)(qrow)  * 4096 + nkt * 32 + g * 8);
    bf16x8 nv1 = *(const bf16x8*)(Vh + (size_t)(16 + qrow) * 4096 + nkt * 32 + g * 8);

    f32x4 accA = __builtin_amdgcn_mfma_f32_16x16x32_bf16(kf0, qf, zero, 0, 0, 0);
    f32x4 accB = __builtin_amdgcn_mfma_f32_16x16x32_bf16(kf1, qf, zero, 0, 0, 0);

    int z0 = kt >> 3, y0 = (kt << 1) & 15;
    int Cc = 495 - 31 * z0 - y0;
    const float* lp = &lut[lanebase + Cc - 4 * g - 4];
    float l0 = lp[0], l1 = lp[1], l2 = lp[2], l3 = lp[3], l4 = lp[4];

    float t0 = fmaf(accA[0], SL, l4);
    float t1 = fmaf(accA[1], SL, l3);
    float t2 = fmaf(accA[2], SL, l2);
    float t3 = fmaf(accA[3], SL, l1);
    float t4 = fmaf(accB[0], SL, l3);
    float t5 = fmaf(accB[1], SL, l2);
    float t6 = fmaf(accB[2], SL, l1);
    float t7 = fmaf(accB[3], SL, l0);

    float cm = fmaxf(fmaxf(fmaxf(t0, t1), fmaxf(t2, t3)),
                     fmaxf(fmaxf(t4, t5), fmaxf(t6, t7)));
    cm = fmaxf(cm, __shfl_xor(cm, 16, 64));
    cm = fmaxf(cm, __shfl_xor(cm, 32, 64));

    if (__any(cm > m2 + 8.f)) {
      float mn   = fmaxf(m2, cm);
      float corr = exp2f(m2 - mn);
      m2 = mn;
      lpart *= corr;
      accO0[0] *= corr; accO0[1] *= corr; accO0[2] *= corr; accO0[3] *= corr;
      accO1[0] *= corr; accO1[1] *= corr; accO1[2] *= corr; accO1[3] *= corr;
    }

    float p0 = exp2f(t0 - m2), p1 = exp2f(t1 - m2);
    float p2 = exp2f(t2 - m2), p3 = exp2f(t3 - m2);
    float p4 = exp2f(t4 - m2), p5 = exp2f(t5 - m2);
    float p6 = exp2f(t6 - m2), p7 = exp2f(t7 - m2);
    lpart += ((p0 + p1) + (p2 + p3)) + ((p4 + p5) + (p6 + p7));

    int w0 = cvtpk(p0, p1), w1 = cvtpk(p2, p3);
    int w2 = cvtpk(p4, p5), w3 = cvtpk(p6, p7);
    int srcA = ((g & 1) << 5) + qrow;
    int srcB = srcA + 16;
    int x0 = __shfl(w0, srcA, 64), x1 = __shfl(w1, srcA, 64);
    int x2 = __shfl(w2, srcA, 64), x3 = __shfl(w3, srcA, 64);
    int y0s = __shfl(w0, srcB, 64), y1s = __shfl(w1, srcB, 64);
    int y2s = __shfl(w2, srcB, 64), y3s = __shfl(w3, srcB, 64);
    bool thi = (g >> 1) != 0;
    union { i32x4 i4; bf16x8 s8; } up;
    up.i4 = (i32x4){ thi ? x2 : x0, thi ? x3 : x1,
                     thi ? y2s : y0s, thi ? y3s : y1s };

    accO0 = __builtin_amdgcn_mfma_f32_16x16x32_bf16(vf0, up.s8, accO0, 0, 0, 0);
    accO1 = __builtin_amdgcn_mfma_f32_16x16x32_bf16(vf1, up.s8, accO1, 0, 0, 0);

    kf0 = nk0; kf1 = nk1; vf0 = nv0; vf1 = nv1;
  }

  float lsum = lpart + __shfl_xor(lpart, 16, 64);
  lsum += __shfl_xor(lsum, 32, 64);

  int lbase = (w * 64 + lane) * 9;
  #pragma unroll
  for (int r = 0; r < 4; r++) { red_o[lbase + r] = accO0[r]; red_o[lbase + 4 + r] = accO1[r]; }
  if (g == 0) { red_ml[0][w][qrow] = m2; red_ml[1][w][qrow] = lsum; }
  __syncthreads();

  if (w == 0) {
    float ml[8];
    float mx = -1e30f;
    #pragma unroll
    for (int wv = 0; wv < 8; wv++) { ml[wv] = red_ml[0][wv][qrow]; mx = fmaxf(mx, ml[wv]); }
    float c[8];
    float L = 0.f;
    #pragma unroll
    for (int wv = 0; wv < 8; wv++) {
      c[wv] = exp2f(ml[wv] - mx);
      L = fmaf(c[wv], red_ml[1][wv][qrow], L);
    }
    float inv = 1.0f / L;
    #pragma unroll
    for (int r = 0; r < 8; r++) {
      float o = 0.f;
      #pragma unroll
      for (int wv = 0; wv < 8; wv++)
        o = fmaf(c[wv], red_o[(wv * 64 + lane) * 9 + r], o);
      int d0 = (r < 4) ? (4 * g + r) : (16 + 4 * g + (r - 4));
      o_sp[(size_t)(d0 * 4 + head) * 4096 + i] = o * inv;
    }
  }
}

// ---- K5: depthwise out projection ----------------------------------------
__global__ __launch_bounds__(256) void dw_out_kernel(
    const float* __restrict__ in, const float* __restrict__ w, float* __restrict__ out) {
  dw_body<false>(in, w, nullptr, out, 16, 256, 4096, 128, blockIdx.x * 256 + threadIdx.x);
}

// ---- K6: pw_out 128->128 + r16 residue + deterministic BN partial sums ----
__global__ __launch_bounds__(256) void pw_out_kernel(
    const float* __restrict__ in, const float* __restrict__ w,
    const float* __restrict__ r16, float* __restrict__ res2,
    float* __restrict__ sums) {
  __shared__ float red[4][2][2];
  int oc0 = (blockIdx.x >> 3) * 2;
  int sb  = blockIdx.x & 7;
  int s0  = (sb * 256 + threadIdx.x) * 2;
  float a00 = 0.f, a01 = 0.f, a10 = 0.f, a11 = 0.f;
  const float* w0 = w + (size_t)oc0 * 128;
  const float* w1 = w0 + 128;
  #pragma unroll 8
  for (int ic = 0; ic < 128; ic++) {
    float xa = in[(size_t)ic * 4096 + s0];
    float xb = in[(size_t)ic * 4096 + s0 + 1];
    float wv0 = w0[ic], wv1 = w1[ic];
    a00 = fmaf(wv0, xa, a00); a01 = fmaf(wv0, xb, a01);
    a10 = fmaf(wv1, xa, a10); a11 = fmaf(wv1, xb, a11);
  }
  size_t ob0 = (size_t)oc0 * 4096 + s0;
  size_t ob1 = ob0 + 4096;
  float r00 = a00 + r16[ob0],     r01 = a01 + r16[ob0 + 1];
  float r10 = a10 + r16[ob1],     r11 = a11 + r16[ob1 + 1];
  res2[ob0] = r00; res2[ob0 + 1] = r01;
  res2[ob1] = r10; res2[ob1 + 1] = r11;
  float s_0 = r00 + r01, q_0 = fmaf(r00, r00, r01 * r01);
  float s_1 = r10 + r11, q_1 = fmaf(r10, r10, r11 * r11);
  #pragma unroll
  for (int off = 32; off; off >>= 1) {
    s_0 += __shfl_down(s_0, off, 64); q_0 += __shfl_down(q_0, off, 64);
    s_1 += __shfl_down(s_1, off, 64); q_1 += __shfl_down(q_1, off, 64);
  }
  int wid = threadIdx.x >> 6;
  if ((threadIdx.x & 63) == 0) {
    red[wid][0][0] = s_0; red[wid][0][1] = q_0;
    red[wid][1][0] = s_1; red[wid][1][1] = q_1;
  }
  __syncthreads();
  if (threadIdx.x < 2) {
    int o = threadIdx.x;
    float st = red[0][o][0] + red[1][o][0] + red[2][o][0] + red[3][o][0];
    float qt = red[0][o][1] + red[1][o][1] + red[2][o][1] + red[3][o][1];
    sums[(oc0 + o) * 8 + sb]        = st;
    sums[1024 + (oc0 + o) * 8 + sb] = qt;
  }
}

// ---- K7: mlp pw with in-block BN-affine finalize + ReLU + residual --------
__global__ __launch_bounds__(256) void pw_mlp_kernel(
    const float* __restrict__ res2, const float* __restrict__ w,
    const float* __restrict__ gamma2, const float* __restrict__ beta2,
    const float* __restrict__ sums, float* __restrict__ out) {
  __shared__ float A[128], Bb[128];
  if (threadIdx.x < 128) {
    int c = threadIdx.x;
    float s = 0.f, q = 0.f;
    #pragma unroll
    for (int sb = 0; sb < 8; sb++) { s += sums[c * 8 + sb]; q += sums[1024 + c * 8 + sb]; }
    float m   = s * (1.0f / 4096.0f);
    float var = q * (1.0f / 4096.0f) - m * m;
    float a   = gamma2[c] * rsqrtf(var + 1e-5f);
    A[c]  = a;
    Bb[c] = beta2[c] - m * a;
  }
  __syncthreads();
  int oc0 = (blockIdx.x >> 3) * 2;
  int sb  = blockIdx.x & 7;
  int s0  = (sb * 256 + threadIdx.x) * 2;
  float a00 = 0.f, a01 = 0.f, a10 = 0.f, a11 = 0.f;
  const float* w0 = w + (size_t)oc0 * 128;
  const float* w1 = w0 + 128;
  #pragma unroll 8
  for (int ic = 0; ic < 128; ic++) {
    float aa = A[ic], bb = Bb[ic];
    float xa = fmaxf(fmaf(res2[(size_t)ic * 4096 + s0], aa, bb), 0.f);
    float xb = fmaxf(fmaf(res2[(size_t)ic * 4096 + s0 + 1], aa, bb), 0.f);
    float wv0 = w0[ic], wv1 = w1[ic];
    a00 = fmaf(wv0, xa, a00); a01 = fmaf(wv0, xb, a01);
    a10 = fmaf(wv1, xa, a10); a11 = fmaf(wv1, xb, a11);
  }
  size_t ob0 = (size_t)oc0 * 4096 + s0;
  size_t ob1 = ob0 + 4096;
  out[ob0]     = a00 + res2[ob0];
  out[ob0 + 1] = a01 + res2[ob0 + 1];
  out[ob1]     = a10 + res2[ob1];
  out[ob1 + 1] = a11 + res2[ob1 + 1];
}

// ---------------------------------------------------------------------------
extern "C" void kernel_launch(void* const* d_in, const int* in_sizes, int n_in,
                              void* d_out, int out_size, void* d_ws, size_t ws_size,
                              hipStream_t stream) {
  (void)in_sizes; (void)n_in; (void)out_size; (void)ws_size;
  const float* x1      = (const float*)d_in[0];
  const float* x2      = (const float*)d_in[1];
  const float* w_ch    = (const float*)d_in[2];
  const float* b_ch    = (const float*)d_in[3];
  const float* gamma_l = (const float*)d_in[4];
  const float* beta_l  = (const float*)d_in[5];
  const float* gamma_h = (const float*)d_in[6];
  const float* beta_h  = (const float*)d_in[7];
  const float* gamma2  = (const float*)d_in[8];
  const float* beta2   = (const float*)d_in[9];
  const float* kv_dw   = (const float*)d_in[10];
  const float* kv_pw   = (const float*)d_in[11];
  const float* q_dw    = (const float*)d_in[12];
  const float* q_pw    = (const float*)d_in[13];
  const float* out_dw  = (const float*)d_in[14];
  const float* out_pw  = (const float*)d_in[15];
  const float* w_mlp   = (const float*)d_in[16];
  const float* rtab    = (const float*)d_in[17];

  float* ws = (float*)d_ws;
  // sizes in FLOATS. Qpk/Kb/Vt each hold 4*4096*32 = 524288 bf16 = 262144 floats.
  float* ab_l = ws + 0;        //    512
  float* ab_h = ws + 512;      //    256
  float* sums = ws + 768;      //   2048
  float* res8 = ws + 2816;     //  65536
  float* kvdw = ws + 68352;    // 131072
  float* qdw  = ws + 199424;   // 524288 -> 723712
  unsigned short* Qpk = (unsigned short*)(ws + 723712);   // 262144 f -> 985856
  unsigned short* Kb  = (unsigned short*)(ws + 985856);   // 262144 f -> 1248000
  unsigned short* Vt  = (unsigned short*)(ws + 1248000);  // 262144 f -> 1510144
  float* r16  = ws + 1510144;  // 524288 -> 2034432
  float* o_sp = ws + 2034432;  // 524288 -> 2558720
  float* odw  = ws + 2558720;  // 524288 -> 3083008
  float* res2 = ws + 3083008;  // 524288 -> 3607296 floats (~14.4 MB)

  bnstat_both_kernel<<<384, 256, 0, stream>>>(x1, x2, gamma_l, beta_l, gamma_h, beta_h,
                                              ab_l, ab_h);
  stageA_kernel<<<2688, 256, 0, stream>>>(x1, x2, w_ch, b_ch, kv_dw, q_dw,
                                          ab_l, ab_h, res8, kvdw, qdw);
  stageB_kernel<<<1280, 512, 0, stream>>>(kvdw, kv_pw, qdw, q_pw, res8,
                                          Kb, Vt, Qpk, r16);
  attn_mfma_kernel<<<1024, 512, 0, stream>>>(Qpk, Kb, Vt, rtab, o_sp);
  dw_out_kernel<<<2048, 256, 0, stream>>>(o_sp, out_dw, odw);
  pw_out_kernel<<<512, 256, 0, stream>>>(odw, out_pw, r16, res2, sums);
  pw_mlp_kernel<<<512, 256, 0, stream>>>(res2, w_mlp, gamma2, beta2, sums, (float*)d_out);
}

// Round 9
// 112.466 us; speedup vs baseline: 1.3990x; 1.0865x over previous
//
#include <hip/hip_runtime.h>
#include <hip/hip_bf16.h>

using f32x4  = __attribute__((ext_vector_type(4))) float;
using bf16x8 = __attribute__((ext_vector_type(8))) short;
using i32x4  = __attribute__((ext_vector_type(4))) int;

static constexpr float SCALE = 0.17677669529663687f; // 32^-0.5
static constexpr float L2E   = 1.4426950408889634f;
static constexpr float SL    = SCALE * L2E;

__device__ inline int cvtpk(float lo, float hi) {
  int r;
  asm("v_cvt_pk_bf16_f32 %0,%1,%2" : "=v"(r) : "v"(lo), "v"(hi));
  return r;
}

// ---- wave+block reduce (sum, sumsq), 256-thread blocks --------------------
__device__ inline void bred2(float& s, float& ss) {
  #pragma unroll
  for (int off = 32; off; off >>= 1) {
    s  += __shfl_down(s, off, 64);
    ss += __shfl_down(ss, off, 64);
  }
  __shared__ float as_[4], ass_[4];
  int wid = threadIdx.x >> 6;
  if ((threadIdx.x & 63) == 0) { as_[wid] = s; ass_[wid] = ss; }
  __syncthreads();
  s  = as_[0] + as_[1] + as_[2] + as_[3];
  ss = ass_[0] + ass_[1] + ass_[2] + ass_[3];
}

// ---- K1: BN stats for x1 and x2 -------------------------------------------
__global__ __launch_bounds__(256) void bnstat_both_kernel(
    const float* __restrict__ x1, const float* __restrict__ x2,
    const float* __restrict__ gl, const float* __restrict__ bl,
    const float* __restrict__ gh, const float* __restrict__ bh,
    float* __restrict__ ab_l, float* __restrict__ ab_h) {
  int b = blockIdx.x;
  const float* src; const float *gamma, *beta; float* ab; int S, C, c;
  if (b < 256) { c = b;       src = x1 + (size_t)c * 512;  S = 512;  C = 256; gamma = gl; beta = bl; ab = ab_l; }
  else         { c = b - 256; src = x2 + (size_t)c * 4096; S = 4096; C = 128; gamma = gh; beta = bh; ab = ab_h; }
  float s = 0.f, ss = 0.f;
  for (int i = threadIdx.x; i < S; i += 256) { float v = src[i]; s += v; ss = fmaf(v, v, ss); }
  bred2(s, ss);
  if (threadIdx.x == 0) {
    float inv = 1.0f / (float)S;
    float m   = s * inv;
    float var = ss * inv - m * m;
    float a   = gamma[c] * rsqrtf(var + 1e-5f);
    ab[c]     = a;
    ab[C + c] = beta[c] - m * a;
  }
}

// ---- depthwise 3x3x3 body -------------------------------------------------
template<bool AFF>
__device__ inline void dw_body(
    const float* __restrict__ in, const float* __restrict__ w,
    const float* __restrict__ ab, float* __restrict__ out,
    int n, int nn, int n3, int C, int t) {
  int c = t / n3, s = t - c * n3;
  int z = s / nn, r = s - z * nn, y = r / n, x = r - y * n;
  const float* src = in + (size_t)c * n3;
  const float* wc  = w + c * 27;
  float a = 1.f, b = 0.f;
  if (AFF) { a = ab[c]; b = ab[C + c]; }
  float acc = 0.f;
  #pragma unroll
  for (int kd = 0; kd < 3; kd++) {
    int zz = z + kd - 1;
    if (zz < 0 || zz >= n) continue;
    #pragma unroll
    for (int kh = 0; kh < 3; kh++) {
      int yy = y + kh - 1;
      if (yy < 0 || yy >= n) continue;
      #pragma unroll
      for (int kw = 0; kw < 3; kw++) {
        int xx = x + kw - 1;
        if (xx < 0 || xx >= n) continue;
        float v = src[(zz * n + yy) * n + xx];
        if (AFF) v = fmaf(v, a, b);
        acc = fmaf(v, wc[kd * 9 + kh * 3 + kw], acc);
      }
    }
  }
  out[t] = acc;
}

// ---- K2: stageA = res8 pointwise | dw_kv | dw_q ---------------------------
__global__ __launch_bounds__(256) void stageA_kernel(
    const float* __restrict__ x1, const float* __restrict__ x2,
    const float* __restrict__ w_ch, const float* __restrict__ b_ch,
    const float* __restrict__ kv_dw, const float* __restrict__ q_dw,
    const float* __restrict__ ab_l, const float* __restrict__ ab_h,
    float* __restrict__ res8, float* __restrict__ kvdw, float* __restrict__ qdw) {
  int b = blockIdx.x;
  if (b < 128) {
    int oc0 = (b >> 1) * 2;
    int s   = (b & 1) * 256 + threadIdx.x;
    float a0 = 0.f, a1 = 0.f;
    const float* w0 = w_ch + (size_t)oc0 * 256;
    const float* w1 = w0 + 256;
    #pragma unroll 8
    for (int ic = 0; ic < 256; ic++) {
      float x = x1[(size_t)ic * 512 + s];
      a0 = fmaf(w0[ic], x, a0);
      a1 = fmaf(w1[ic], x, a1);
    }
    res8[(size_t)oc0 * 512 + s]       = a0 + b_ch[oc0];
    res8[(size_t)(oc0 + 1) * 512 + s] = a1 + b_ch[oc0 + 1];
  } else if (b < 640) {
    dw_body<true>(x1, kv_dw, ab_l, kvdw, 8, 64, 512, 256, (b - 128) * 256 + threadIdx.x);
  } else {
    dw_body<true>(x2, q_dw, ab_h, qdw, 16, 256, 4096, 128, (b - 640) * 256 + threadIdx.x);
  }
}

// ---- trilinear helpers ----------------------------------------------------
__device__ inline void icoef8(int o, int& lo, int& hi, float& w) {
  float p = (float)o * (7.0f / 15.0f);
  int l = (int)floorf(p);
  if (l > 7) l = 7;
  int h = l + 1 > 7 ? 7 : l + 1;
  w  = p - (float)l;
  lo = l; hi = h;
}

__device__ inline float trilin8(const float* __restrict__ p,
                                int z0, int z1, float wz,
                                int y0, int y1, float wy,
                                int x0, int x1, float wx) {
  float c00 = p[(z0*8+y0)*8+x0]*(1.f-wx) + p[(z0*8+y0)*8+x1]*wx;
  float c01 = p[(z0*8+y1)*8+x0]*(1.f-wx) + p[(z0*8+y1)*8+x1]*wx;
  float c10 = p[(z1*8+y0)*8+x0]*(1.f-wx) + p[(z1*8+y0)*8+x1]*wx;
  float c11 = p[(z1*8+y1)*8+x0]*(1.f-wx) + p[(z1*8+y1)*8+x1]*wx;
  float c0 = c00*(1.f-wy) + c01*wy;
  float c1 = c10*(1.f-wy) + c11*wy;
  return c0*(1.f-wz) + c1*wz;
}

// ---- K3: stageB = pw_kv+interp->Kb/Vt | pw_q->Qpk | interp_res ------------
__global__ __launch_bounds__(512) void stageB_kernel(
    const float* __restrict__ kvdw, const float* __restrict__ kv_pw,
    const float* __restrict__ qdw, const float* __restrict__ q_pw,
    const float* __restrict__ res8,
    unsigned short* __restrict__ Kb, unsigned short* __restrict__ Vt,
    unsigned short* __restrict__ Qpk, float* __restrict__ r16) {
  __shared__ float sm[2][512];
  int b = blockIdx.x;
  int tid = threadIdx.x;
  if (b < 128) {
    int kc0 = b * 2;
    int s = tid;
    float a0 = 0.f, a1 = 0.f;
    const float* w0 = kv_pw + (size_t)kc0 * 256;
    const float* w1 = w0 + 256;
    #pragma unroll 8
    for (int ic = 0; ic < 256; ic++) {
      float x = kvdw[(size_t)ic * 512 + s];
      a0 = fmaf(w0[ic], x, a0);
      a1 = fmaf(w1[ic], x, a1);
    }
    sm[0][s] = a0; sm[1][s] = a1;
    __syncthreads();
    #pragma unroll
    for (int r = 0; r < 16; r++) {
      int u  = r * 512 + tid;
      int cl = u >> 12, j = u & 4095;
      int z = j >> 8, y = (j >> 4) & 15, x = j & 15;
      int z0,z1,y0,y1,x0,x1; float wz,wy,wx;
      icoef8(z, z0, z1, wz); icoef8(y, y0, y1, wy); icoef8(x, x0, x1, wx);
      float val = trilin8(sm[cl], z0, z1, wz, y0, y1, wy, x0, x1, wx);
      __hip_bfloat16 bv = __float2bfloat16(val);
      unsigned short us = *reinterpret_cast<unsigned short*>(&bv);
      int kc = kc0 + cl;
      int c  = kc & 127;
      int head = c & 3, dh = c >> 2;
      if (kc < 128) Kb[((size_t)(head << 12) + j) * 32 + dh] = us;
      else          Vt[((size_t)(head * 32) + dh) * 4096 + j] = us;
    }
  } else if (b < 256) {
    int bb   = b - 128;
    int head = bb >> 5;
    int r2   = bb & 31;
    int dh0  = (r2 >> 3) * 8;
    int i    = (r2 & 7) * 512 + tid;
    float acc[8];
    #pragma unroll
    for (int e = 0; e < 8; e++) acc[e] = 0.f;
    #pragma unroll 4
    for (int ic = 0; ic < 128; ic++) {
      float x = qdw[(size_t)ic * 4096 + i];
      #pragma unroll
      for (int e = 0; e < 8; e++)
        acc[e] = fmaf(q_pw[(size_t)((dh0 + e) * 4 + head) * 128 + ic], x, acc[e]);
    }
    i32x4 pk = { cvtpk(acc[0], acc[1]), cvtpk(acc[2], acc[3]),
                 cvtpk(acc[4], acc[5]), cvtpk(acc[6], acc[7]) };
    *reinterpret_cast<i32x4*>(Qpk + ((size_t)(head << 12) + i) * 32 + dh0) = pk;
  } else {
    int t = (b - 256) * 512 + tid;   // 524288
    int s = t & 4095, c = t >> 12;
    int z = s >> 8, y = (s >> 4) & 15, x = s & 15;
    int z0,z1,y0,y1,x0,x1; float wz,wy,wx;
    icoef8(z, z0, z1, wz); icoef8(y, y0, y1, wy); icoef8(x, x0, x1, wx);
    r16[t] = trilin8(res8 + c * 512, z0, z1, wz, y0, y1, wy, x0, x1, wx);
  }
}

// ---- K4: MFMA flash attention with LDS-shared K/V tiles -------------------
// grid 1024 = head(4) x qgroup(32) x ksplit(8); block = 512 thr = 8 waves.
// The 8 waves cover 8 q-strips (128 q) and SHARE the block's 512-key slice:
// each 32-key K/V tile (8 KB) is staged once into double-buffered LDS and
// consumed by all 8 waves -> L2 K/V traffic drops 16x vs per-wave loads.
// Each wave emits an independent (16 q x 512 key) partial; attn_reduce
// combines the 8 key-slices.
__global__ __launch_bounds__(512, 4) void attn_mfma_kernel(
    const unsigned short* __restrict__ Qpk, const unsigned short* __restrict__ Kb,
    const unsigned short* __restrict__ Vt, const float* __restrict__ table,
    float* __restrict__ part_o, float* __restrict__ part_m, float* __restrict__ part_l) {
  __shared__ float lut[992];
  __shared__ unsigned short kvs[2][4096];  // [buf][K tile 2048 | V tile 2048]

  int head = blockIdx.x >> 8;
  int rem  = blockIdx.x & 255;
  int qg   = rem >> 3;
  int ksb  = rem & 7;
  int tid  = threadIdx.x;

  for (int u = tid; u < 991; u += 512) {
    int p = (u < 15) ? (u - 15 + 29791) : (u - 15);
    lut[u] = table[p * 4 + head] * SL;
  }

  int w    = tid >> 6;
  int lane = tid & 63;
  int qrow = lane & 15;
  int g    = lane >> 4;
  int i    = qg * 128 + w * 16 + qrow;       // global query index
  int iz = i >> 8, iy = (i >> 4) & 15, ix = i & 15;
  int lanebase = iz * 31 + iy + ix;

  bf16x8 qf = *(const bf16x8*)(Qpk + ((size_t)(head << 12) + i) * 32 + g * 8);

  const unsigned short* Kh = Kb + (size_t)head * 4096 * 32;
  const unsigned short* Vh = Vt + (size_t)head * 32 * 4096;

  int kt0 = ksb * 16;                        // first 32-key tile of this slice

  // ---- staging source (pre-swizzled global addr, linear LDS dst = tid*8) --
  // LDS slot layout: K row `key` slot s at key*32 + s*8; V at 2048 + dh*32 + s*8.
  // slot s holds dh-group (s ^ ((row>>1)&3)) so reads are 2-way-bank clean.
  const unsigned short* src;
  size_t sstride;
  if (tid < 256) {
    int key = tid >> 2, s = tid & 3;
    int gp  = s ^ ((key >> 1) & 3);
    src = Kh + (size_t)(kt0 * 32 + key) * 32 + gp * 8;
    sstride = 32 * 32;                       // 32 keys x 32 dh per tile
  } else {
    int tt = tid - 256;
    int dh = tt >> 2, s = tt & 3;
    int gp = s ^ ((dh >> 1) & 3);
    src = Vh + (size_t)dh * 4096 + kt0 * 32 + gp * 8;
    sstride = 32;                            // 32 keys per tile along row
  }
  int t8 = tid * 8;                          // linear LDS dst (ushorts)

  // read-side swizzled offsets (constant per lane)
  int sw    = (qrow >> 1) & 3;
  int k0off = qrow * 32 + ((g ^ sw) * 8);
  int k1off = k0off + 512;                   // key + 16
  int v0off = 2048 + k0off;
  int v1off = v0off + 512;                   // dh + 16

  // prologue: stage tile 0 into buf 0
  {
    bf16x8 s0 = *(const bf16x8*)src; src += sstride;
    *(bf16x8*)(&kvs[0][t8]) = s0;
  }
  __syncthreads();

  f32x4 zero = {0.f, 0.f, 0.f, 0.f};
  f32x4 accO0 = zero, accO1 = zero;
  float m2 = -1e30f, lpart = 0.f;
  int cur = 0;

  for (int ktl = 0; ktl < 16; ktl++) {
    int kt = kt0 + ktl;
    bf16x8 stg;
    if (ktl < 15) { stg = *(const bf16x8*)src; src += sstride; }

    bf16x8 kf0 = *(const bf16x8*)(&kvs[cur][k0off]);
    bf16x8 kf1 = *(const bf16x8*)(&kvs[cur][k1off]);
    bf16x8 vf0 = *(const bf16x8*)(&kvs[cur][v0off]);
    bf16x8 vf1 = *(const bf16x8*)(&kvs[cur][v1off]);

    f32x4 accA = __builtin_amdgcn_mfma_f32_16x16x32_bf16(kf0, qf, zero, 0, 0, 0);
    f32x4 accB = __builtin_amdgcn_mfma_f32_16x16x32_bf16(kf1, qf, zero, 0, 0, 0);

    int z0 = kt >> 3, y0 = (kt << 1) & 15;
    int Cc = 495 - 31 * z0 - y0;
    const float* lp = &lut[lanebase + Cc - 4 * g - 4];
    float l0 = lp[0], l1 = lp[1], l2 = lp[2], l3 = lp[3], l4 = lp[4];

    float t0 = fmaf(accA[0], SL, l4);
    float t1 = fmaf(accA[1], SL, l3);
    float t2 = fmaf(accA[2], SL, l2);
    float t3 = fmaf(accA[3], SL, l1);
    float t4 = fmaf(accB[0], SL, l3);
    float t5 = fmaf(accB[1], SL, l2);
    float t6 = fmaf(accB[2], SL, l1);
    float t7 = fmaf(accB[3], SL, l0);

    float cm = fmaxf(fmaxf(fmaxf(t0, t1), fmaxf(t2, t3)),
                     fmaxf(fmaxf(t4, t5), fmaxf(t6, t7)));
    cm = fmaxf(cm, __shfl_xor(cm, 16, 64));
    cm = fmaxf(cm, __shfl_xor(cm, 32, 64));

    if (__any(cm > m2 + 8.f)) {
      float mn   = fmaxf(m2, cm);
      float corr = exp2f(m2 - mn);
      m2 = mn;
      lpart *= corr;
      accO0[0] *= corr; accO0[1] *= corr; accO0[2] *= corr; accO0[3] *= corr;
      accO1[0] *= corr; accO1[1] *= corr; accO1[2] *= corr; accO1[3] *= corr;
    }

    float p0 = exp2f(t0 - m2), p1 = exp2f(t1 - m2);
    float p2 = exp2f(t2 - m2), p3 = exp2f(t3 - m2);
    float p4 = exp2f(t4 - m2), p5 = exp2f(t5 - m2);
    float p6 = exp2f(t6 - m2), p7 = exp2f(t7 - m2);
    lpart += ((p0 + p1) + (p2 + p3)) + ((p4 + p5) + (p6 + p7));

    int w0 = cvtpk(p0, p1), w1 = cvtpk(p2, p3);
    int w2 = cvtpk(p4, p5), w3 = cvtpk(p6, p7);
    int srcA = ((g & 1) << 5) + qrow;
    int srcB = srcA + 16;
    int x0 = __shfl(w0, srcA, 64), x1 = __shfl(w1, srcA, 64);
    int x2 = __shfl(w2, srcA, 64), x3 = __shfl(w3, srcA, 64);
    int y0s = __shfl(w0, srcB, 64), y1s = __shfl(w1, srcB, 64);
    int y2s = __shfl(w2, srcB, 64), y3s = __shfl(w3, srcB, 64);
    bool thi = (g >> 1) != 0;
    union { i32x4 i4; bf16x8 s8; } up;
    up.i4 = (i32x4){ thi ? x2 : x0, thi ? x3 : x1,
                     thi ? y2s : y0s, thi ? y3s : y1s };

    accO0 = __builtin_amdgcn_mfma_f32_16x16x32_bf16(vf0, up.s8, accO0, 0, 0, 0);
    accO1 = __builtin_amdgcn_mfma_f32_16x16x32_bf16(vf1, up.s8, accO1, 0, 0, 0);

    if (ktl < 15) *(bf16x8*)(&kvs[cur ^ 1][t8]) = stg;
    __syncthreads();
    cur ^= 1;
  }

  float lsum = lpart + __shfl_xor(lpart, 16, 64);
  lsum += __shfl_xor(lsum, 32, 64);

  // per-wave partial write (wave = complete 16q x 512key slice)
  int base = head * 8 + ksb;
  if (g == 0) {
    part_m[base * 4096 + i] = m2;
    part_l[base * 4096 + i] = lsum;
  }
  #pragma unroll
  for (int r = 0; r < 4; r++) {
    part_o[(size_t)(base * 32 + 4 * g + r) * 4096 + i]      = accO0[r];
    part_o[(size_t)(base * 32 + 16 + 4 * g + r) * 4096 + i] = accO1[r];
  }
}

// ---- K4b: combine the 8 key-slice partials, write channel-spatial ---------
__global__ __launch_bounds__(256) void attn_reduce_kernel(
    const float* __restrict__ part_o, const float* __restrict__ part_m,
    const float* __restrict__ part_l, float* __restrict__ o_sp) {
  int t = blockIdx.x * 256 + threadIdx.x;  // 16384
  int i = t & 4095, head = t >> 12;
  float mk[8], mx = -1e30f;
  #pragma unroll
  for (int ks = 0; ks < 8; ks++) { mk[ks] = part_m[(head*8+ks)*4096 + i]; mx = fmaxf(mx, mk[ks]); }
  float c[8], L = 0.f;
  #pragma unroll
  for (int ks = 0; ks < 8; ks++) {
    c[ks] = exp2f(mk[ks] - mx);              // all values in log2 domain
    L = fmaf(c[ks], part_l[(head*8+ks)*4096 + i], L);
  }
  float invL = 1.f / L;
  #pragma unroll
  for (int d = 0; d < 32; d++) {
    float acc = 0.f;
    #pragma unroll
    for (int ks = 0; ks < 8; ks++)
      acc = fmaf(c[ks], part_o[(size_t)((head*8+ks)*32 + d) * 4096 + i], acc);
    o_sp[(size_t)(d * 4 + head) * 4096 + i] = acc * invL;
  }
}

// ---- K5: depthwise out projection ----------------------------------------
__global__ __launch_bounds__(256) void dw_out_kernel(
    const float* __restrict__ in, const float* __restrict__ w, float* __restrict__ out) {
  dw_body<false>(in, w, nullptr, out, 16, 256, 4096, 128, blockIdx.x * 256 + threadIdx.x);
}

// ---- K6: pw_out 128->128 + r16 residue + deterministic BN partial sums ----
__global__ __launch_bounds__(256) void pw_out_kernel(
    const float* __restrict__ in, const float* __restrict__ w,
    const float* __restrict__ r16, float* __restrict__ res2,
    float* __restrict__ sums) {
  __shared__ float red[4][2][2];
  int oc0 = (blockIdx.x >> 3) * 2;
  int sb  = blockIdx.x & 7;
  int s0  = (sb * 256 + threadIdx.x) * 2;
  float a00 = 0.f, a01 = 0.f, a10 = 0.f, a11 = 0.f;
  const float* w0 = w + (size_t)oc0 * 128;
  const float* w1 = w0 + 128;
  #pragma unroll 8
  for (int ic = 0; ic < 128; ic++) {
    float xa = in[(size_t)ic * 4096 + s0];
    float xb = in[(size_t)ic * 4096 + s0 + 1];
    float wv0 = w0[ic], wv1 = w1[ic];
    a00 = fmaf(wv0, xa, a00); a01 = fmaf(wv0, xb, a01);
    a10 = fmaf(wv1, xa, a10); a11 = fmaf(wv1, xb, a11);
  }
  size_t ob0 = (size_t)oc0 * 4096 + s0;
  size_t ob1 = ob0 + 4096;
  float r00 = a00 + r16[ob0],     r01 = a01 + r16[ob0 + 1];
  float r10 = a10 + r16[ob1],     r11 = a11 + r16[ob1 + 1];
  res2[ob0] = r00; res2[ob0 + 1] = r01;
  res2[ob1] = r10; res2[ob1 + 1] = r11;
  float s_0 = r00 + r01, q_0 = fmaf(r00, r00, r01 * r01);
  float s_1 = r10 + r11, q_1 = fmaf(r10, r10, r11 * r11);
  #pragma unroll
  for (int off = 32; off; off >>= 1) {
    s_0 += __shfl_down(s_0, off, 64); q_0 += __shfl_down(q_0, off, 64);
    s_1 += __shfl_down(s_1, off, 64); q_1 += __shfl_down(q_1, off, 64);
  }
  int wid = threadIdx.x >> 6;
  if ((threadIdx.x & 63) == 0) {
    red[wid][0][0] = s_0; red[wid][0][1] = q_0;
    red[wid][1][0] = s_1; red[wid][1][1] = q_1;
  }
  __syncthreads();
  if (threadIdx.x < 2) {
    int o = threadIdx.x;
    float st = red[0][o][0] + red[1][o][0] + red[2][o][0] + red[3][o][0];
    float qt = red[0][o][1] + red[1][o][1] + red[2][o][1] + red[3][o][1];
    sums[(oc0 + o) * 8 + sb]        = st;
    sums[1024 + (oc0 + o) * 8 + sb] = qt;
  }
}

// ---- K7: mlp pw with in-block BN-affine finalize + ReLU + residual --------
__global__ __launch_bounds__(256) void pw_mlp_kernel(
    const float* __restrict__ res2, const float* __restrict__ w,
    const float* __restrict__ gamma2, const float* __restrict__ beta2,
    const float* __restrict__ sums, float* __restrict__ out) {
  __shared__ float A[128], Bb[128];
  if (threadIdx.x < 128) {
    int c = threadIdx.x;
    float s = 0.f, q = 0.f;
    #pragma unroll
    for (int sb = 0; sb < 8; sb++) { s += sums[c * 8 + sb]; q += sums[1024 + c * 8 + sb]; }
    float m   = s * (1.0f / 4096.0f);
    float var = q * (1.0f / 4096.0f) - m * m;
    float a   = gamma2[c] * rsqrtf(var + 1e-5f);
    A[c]  = a;
    Bb[c] = beta2[c] - m * a;
  }
  __syncthreads();
  int oc0 = (blockIdx.x >> 3) * 2;
  int sb  = blockIdx.x & 7;
  int s0  = (sb * 256 + threadIdx.x) * 2;
  float a00 = 0.f, a01 = 0.f, a10 = 0.f, a11 = 0.f;
  const float* w0 = w + (size_t)oc0 * 128;
  const float* w1 = w0 + 128;
  #pragma unroll 8
  for (int ic = 0; ic < 128; ic++) {
    float aa = A[ic], bb = Bb[ic];
    float xa = fmaxf(fmaf(res2[(size_t)ic * 4096 + s0], aa, bb), 0.f);
    float xb = fmaxf(fmaf(res2[(size_t)ic * 4096 + s0 + 1], aa, bb), 0.f);
    float wv0 = w0[ic], wv1 = w1[ic];
    a00 = fmaf(wv0, xa, a00); a01 = fmaf(wv0, xb, a01);
    a10 = fmaf(wv1, xa, a10); a11 = fmaf(wv1, xb, a11);
  }
  size_t ob0 = (size_t)oc0 * 4096 + s0;
  size_t ob1 = ob0 + 4096;
  out[ob0]     = a00 + res2[ob0];
  out[ob0 + 1] = a01 + res2[ob0 + 1];
  out[ob1]     = a10 + res2[ob1];
  out[ob1 + 1] = a11 + res2[ob1 + 1];
}

// ---------------------------------------------------------------------------
extern "C" void kernel_launch(void* const* d_in, const int* in_sizes, int n_in,
                              void* d_out, int out_size, void* d_ws, size_t ws_size,
                              hipStream_t stream) {
  (void)in_sizes; (void)n_in; (void)out_size; (void)ws_size;
  const float* x1      = (const float*)d_in[0];
  const float* x2      = (const float*)d_in[1];
  const float* w_ch    = (const float*)d_in[2];
  const float* b_ch    = (const float*)d_in[3];
  const float* gamma_l = (const float*)d_in[4];
  const float* beta_l  = (const float*)d_in[5];
  const float* gamma_h = (const float*)d_in[6];
  const float* beta_h  = (const float*)d_in[7];
  const float* gamma2  = (const float*)d_in[8];
  const float* beta2   = (const float*)d_in[9];
  const float* kv_dw   = (const float*)d_in[10];
  const float* kv_pw   = (const float*)d_in[11];
  const float* q_dw    = (const float*)d_in[12];
  const float* q_pw    = (const float*)d_in[13];
  const float* out_dw  = (const float*)d_in[14];
  const float* out_pw  = (const float*)d_in[15];
  const float* w_mlp   = (const float*)d_in[16];
  const float* rtab    = (const float*)d_in[17];

  float* ws = (float*)d_ws;
  // sizes in FLOATS. Qpk/Kb/Vt each hold 4*4096*32 = 524288 bf16 = 262144 floats.
  float* ab_l = ws + 0;        //    512
  float* ab_h = ws + 512;      //    256
  float* sums = ws + 768;      //   2048
  float* res8 = ws + 2816;     //  65536
  float* kvdw = ws + 68352;    // 131072
  float* qdw  = ws + 199424;   // 524288 -> 723712
  unsigned short* Qpk = (unsigned short*)(ws + 723712);   // 262144 f -> 985856
  unsigned short* Kb  = (unsigned short*)(ws + 985856);   // 262144 f -> 1248000
  unsigned short* Vt  = (unsigned short*)(ws + 1248000);  // 262144 f -> 1510144
  float* r16  = ws + 1510144;  // 524288 -> 2034432
  float* o_sp = ws + 2034432;  // 524288 -> 2558720
  float* odw  = ws + 2558720;  // 524288 -> 3083008
  float* res2 = ws + 3083008;  // 524288 -> 3607296
  float* part_o = ws + 3607296; // 4194304 -> 7801600
  float* part_m = ws + 7801600; // 131072  -> 7932672
  float* part_l = ws + 7932672; // 131072  -> 8063744 floats (~32.3 MB)

  bnstat_both_kernel<<<384, 256, 0, stream>>>(x1, x2, gamma_l, beta_l, gamma_h, beta_h,
                                              ab_l, ab_h);
  stageA_kernel<<<2688, 256, 0, stream>>>(x1, x2, w_ch, b_ch, kv_dw, q_dw,
                                          ab_l, ab_h, res8, kvdw, qdw);
  stageB_kernel<<<1280, 512, 0, stream>>>(kvdw, kv_pw, qdw, q_pw, res8,
                                          Kb, Vt, Qpk, r16);
  attn_mfma_kernel<<<1024, 512, 0, stream>>>(Qpk, Kb, Vt, rtab,
                                             part_o, part_m, part_l);
  attn_reduce_kernel<<<64, 256, 0, stream>>>(part_o, part_m, part_l, o_sp);
  dw_out_kernel<<<2048, 256, 0, stream>>>(o_sp, out_dw, odw);
  pw_out_kernel<<<512, 256, 0, stream>>>(odw, out_pw, r16, res2, sums);
  pw_mlp_kernel<<<512, 256, 0, stream>>>(res2, w_mlp, gamma2, beta2, sums, (float*)d_out);
}

// Round 10
// 109.145 us; speedup vs baseline: 1.4415x; 1.0304x over previous
//
#include <hip/hip_runtime.h>
#include <hip/hip_bf16.h>

using f32x4  = __attribute__((ext_vector_type(4))) float;
using bf16x8 = __attribute__((ext_vector_type(8))) short;
using i32x4  = __attribute__((ext_vector_type(4))) int;

static constexpr float SCALE = 0.17677669529663687f; // 32^-0.5
static constexpr float L2E   = 1.4426950408889634f;
static constexpr float SL    = SCALE * L2E;

__device__ inline int cvtpk(float lo, float hi) {
  int r;
  asm("v_cvt_pk_bf16_f32 %0,%1,%2" : "=v"(r) : "v"(lo), "v"(hi));
  return r;
}

// ---- wave+block reduce (sum, sumsq), 256-thread blocks --------------------
__device__ inline void bred2(float& s, float& ss) {
  #pragma unroll
  for (int off = 32; off; off >>= 1) {
    s  += __shfl_down(s, off, 64);
    ss += __shfl_down(ss, off, 64);
  }
  __shared__ float as_[4], ass_[4];
  int wid = threadIdx.x >> 6;
  if ((threadIdx.x & 63) == 0) { as_[wid] = s; ass_[wid] = ss; }
  __syncthreads();
  s  = as_[0] + as_[1] + as_[2] + as_[3];
  ss = ass_[0] + ass_[1] + ass_[2] + ass_[3];
}

// ---- K1: BN stats for x1 and x2 -------------------------------------------
__global__ __launch_bounds__(256) void bnstat_both_kernel(
    const float* __restrict__ x1, const float* __restrict__ x2,
    const float* __restrict__ gl, const float* __restrict__ bl,
    const float* __restrict__ gh, const float* __restrict__ bh,
    float* __restrict__ ab_l, float* __restrict__ ab_h) {
  int b = blockIdx.x;
  const float* src; const float *gamma, *beta; float* ab; int S, C, c;
  if (b < 256) { c = b;       src = x1 + (size_t)c * 512;  S = 512;  C = 256; gamma = gl; beta = bl; ab = ab_l; }
  else         { c = b - 256; src = x2 + (size_t)c * 4096; S = 4096; C = 128; gamma = gh; beta = bh; ab = ab_h; }
  float s = 0.f, ss = 0.f;
  for (int i = threadIdx.x; i < S; i += 256) { float v = src[i]; s += v; ss = fmaf(v, v, ss); }
  bred2(s, ss);
  if (threadIdx.x == 0) {
    float inv = 1.0f / (float)S;
    float m   = s * inv;
    float var = ss * inv - m * m;
    float a   = gamma[c] * rsqrtf(var + 1e-5f);
    ab[c]     = a;
    ab[C + c] = beta[c] - m * a;
  }
}

// ---- depthwise 3x3x3 body -------------------------------------------------
template<bool AFF>
__device__ inline void dw_body(
    const float* __restrict__ in, const float* __restrict__ w,
    const float* __restrict__ ab, float* __restrict__ out,
    int n, int nn, int n3, int C, int t) {
  int c = t / n3, s = t - c * n3;
  int z = s / nn, r = s - z * nn, y = r / n, x = r - y * n;
  const float* src = in + (size_t)c * n3;
  const float* wc  = w + c * 27;
  float a = 1.f, b = 0.f;
  if (AFF) { a = ab[c]; b = ab[C + c]; }
  float acc = 0.f;
  #pragma unroll
  for (int kd = 0; kd < 3; kd++) {
    int zz = z + kd - 1;
    if (zz < 0 || zz >= n) continue;
    #pragma unroll
    for (int kh = 0; kh < 3; kh++) {
      int yy = y + kh - 1;
      if (yy < 0 || yy >= n) continue;
      #pragma unroll
      for (int kw = 0; kw < 3; kw++) {
        int xx = x + kw - 1;
        if (xx < 0 || xx >= n) continue;
        float v = src[(zz * n + yy) * n + xx];
        if (AFF) v = fmaf(v, a, b);
        acc = fmaf(v, wc[kd * 9 + kh * 3 + kw], acc);
      }
    }
  }
  out[t] = acc;
}

// ---- K2: stageA = res8 pointwise | dw_kv | dw_q ---------------------------
__global__ __launch_bounds__(256) void stageA_kernel(
    const float* __restrict__ x1, const float* __restrict__ x2,
    const float* __restrict__ w_ch, const float* __restrict__ b_ch,
    const float* __restrict__ kv_dw, const float* __restrict__ q_dw,
    const float* __restrict__ ab_l, const float* __restrict__ ab_h,
    float* __restrict__ res8, float* __restrict__ kvdw, float* __restrict__ qdw) {
  int b = blockIdx.x;
  if (b < 128) {
    int oc0 = (b >> 1) * 2;
    int s   = (b & 1) * 256 + threadIdx.x;
    float a0 = 0.f, a1 = 0.f;
    const float* w0 = w_ch + (size_t)oc0 * 256;
    const float* w1 = w0 + 256;
    #pragma unroll 8
    for (int ic = 0; ic < 256; ic++) {
      float x = x1[(size_t)ic * 512 + s];
      a0 = fmaf(w0[ic], x, a0);
      a1 = fmaf(w1[ic], x, a1);
    }
    res8[(size_t)oc0 * 512 + s]       = a0 + b_ch[oc0];
    res8[(size_t)(oc0 + 1) * 512 + s] = a1 + b_ch[oc0 + 1];
  } else if (b < 640) {
    dw_body<true>(x1, kv_dw, ab_l, kvdw, 8, 64, 512, 256, (b - 128) * 256 + threadIdx.x);
  } else {
    dw_body<true>(x2, q_dw, ab_h, qdw, 16, 256, 4096, 128, (b - 640) * 256 + threadIdx.x);
  }
}

// ---- trilinear helpers ----------------------------------------------------
__device__ inline void icoef8(int o, int& lo, int& hi, float& w) {
  float p = (float)o * (7.0f / 15.0f);
  int l = (int)floorf(p);
  if (l > 7) l = 7;
  int h = l + 1 > 7 ? 7 : l + 1;
  w  = p - (float)l;
  lo = l; hi = h;
}

__device__ inline float trilin8(const float* __restrict__ p,
                                int z0, int z1, float wz,
                                int y0, int y1, float wy,
                                int x0, int x1, float wx) {
  float c00 = p[(z0*8+y0)*8+x0]*(1.f-wx) + p[(z0*8+y0)*8+x1]*wx;
  float c01 = p[(z0*8+y1)*8+x0]*(1.f-wx) + p[(z0*8+y1)*8+x1]*wx;
  float c10 = p[(z1*8+y0)*8+x0]*(1.f-wx) + p[(z1*8+y0)*8+x1]*wx;
  float c11 = p[(z1*8+y1)*8+x0]*(1.f-wx) + p[(z1*8+y1)*8+x1]*wx;
  float c0 = c00*(1.f-wy) + c01*wy;
  float c1 = c10*(1.f-wy) + c11*wy;
  return c0*(1.f-wz) + c1*wz;
}

// ---- K3: stageB = pw_kv+interp->Kb/Vt | pw_q->Qpk | interp_res ------------
// Kb rows are PERMUTED within each 32-key chunk so that the attn S^T output
// registers land on keys g*8+e in-lane (zero-shuffle PV A-fragment):
//   store_row(k) = 4*(k>>3) + (k&3) + ((k&4) ? 16 : 0)
__global__ __launch_bounds__(512) void stageB_kernel(
    const float* __restrict__ kvdw, const float* __restrict__ kv_pw,
    const float* __restrict__ qdw, const float* __restrict__ q_pw,
    const float* __restrict__ res8,
    unsigned short* __restrict__ Kb, unsigned short* __restrict__ Vt,
    unsigned short* __restrict__ Qpk, float* __restrict__ r16) {
  __shared__ float sm[2][512];
  int b = blockIdx.x;
  int tid = threadIdx.x;
  if (b < 128) {
    int kc0 = b * 2;
    int s = tid;
    float a0 = 0.f, a1 = 0.f;
    const float* w0 = kv_pw + (size_t)kc0 * 256;
    const float* w1 = w0 + 256;
    #pragma unroll 8
    for (int ic = 0; ic < 256; ic++) {
      float x = kvdw[(size_t)ic * 512 + s];
      a0 = fmaf(w0[ic], x, a0);
      a1 = fmaf(w1[ic], x, a1);
    }
    sm[0][s] = a0; sm[1][s] = a1;
    __syncthreads();
    #pragma unroll
    for (int r = 0; r < 16; r++) {
      int u  = r * 512 + tid;
      int cl = u >> 12, j = u & 4095;
      int z = j >> 8, y = (j >> 4) & 15, x = j & 15;
      int z0,z1,y0,y1,x0,x1; float wz,wy,wx;
      icoef8(z, z0, z1, wz); icoef8(y, y0, y1, wy); icoef8(x, x0, x1, wx);
      float val = trilin8(sm[cl], z0, z1, wz, y0, y1, wy, x0, x1, wx);
      __hip_bfloat16 bv = __float2bfloat16(val);
      unsigned short us = *reinterpret_cast<unsigned short*>(&bv);
      int kc = kc0 + cl;
      int c  = kc & 127;
      int head = c & 3, dh = c >> 2;
      if (kc < 128) {
        int k  = j & 31;
        int jp = (j & ~31) | (((k >> 3) << 2) + (k & 3) + ((k & 4) ? 16 : 0));
        Kb[((size_t)(head << 12) + jp) * 32 + dh] = us;
      } else {
        Vt[((size_t)(head * 32) + dh) * 4096 + j] = us;
      }
    }
  } else if (b < 256) {
    int bb   = b - 128;
    int head = bb >> 5;
    int r2   = bb & 31;
    int dh0  = (r2 >> 3) * 8;
    int i    = (r2 & 7) * 512 + tid;
    float acc[8];
    #pragma unroll
    for (int e = 0; e < 8; e++) acc[e] = 0.f;
    #pragma unroll 4
    for (int ic = 0; ic < 128; ic++) {
      float x = qdw[(size_t)ic * 4096 + i];
      #pragma unroll
      for (int e = 0; e < 8; e++)
        acc[e] = fmaf(q_pw[(size_t)((dh0 + e) * 4 + head) * 128 + ic], x, acc[e]);
    }
    i32x4 pk = { cvtpk(acc[0], acc[1]), cvtpk(acc[2], acc[3]),
                 cvtpk(acc[4], acc[5]), cvtpk(acc[6], acc[7]) };
    *reinterpret_cast<i32x4*>(Qpk + ((size_t)(head << 12) + i) * 32 + dh0) = pk;
  } else {
    int t = (b - 256) * 512 + tid;   // 524288
    int s = t & 4095, c = t >> 12;
    int z = s >> 8, y = (s >> 4) & 15, x = s & 15;
    int z0,z1,y0,y1,x0,x1; float wz,wy,wx;
    icoef8(z, z0, z1, wz); icoef8(y, y0, y1, wy); icoef8(x, x0, x1, wx);
    r16[t] = trilin8(res8 + c * 512, z0, z1, wz, y0, y1, wy, x0, x1, wx);
  }
}

// ---- K4: MFMA flash attention, LDS-shared K/V, zero-shuffle PV ------------
// grid 1024 = head(4) x qgroup(32) x ksplit(8); block = 512 thr = 8 waves.
// K rows permuted (stageB) so S^T regs = keys g*8+e in-lane; PV computed as
// O = mfma(A=P, B=V) -> P A-frag is 4 cvtpk of the lane's own p's, no shfl.
__global__ __launch_bounds__(512, 4) void attn_mfma_kernel(
    const unsigned short* __restrict__ Qpk, const unsigned short* __restrict__ Kb,
    const unsigned short* __restrict__ Vt, const float* __restrict__ table,
    float* __restrict__ part_o, float* __restrict__ part_m, float* __restrict__ part_l) {
  __shared__ float lut[992];
  __shared__ unsigned short kvs[2][4096];  // [buf][K tile 2048 | V tile 2048]

  int head = blockIdx.x >> 8;
  int rem  = blockIdx.x & 255;
  int qg   = rem >> 3;
  int ksb  = rem & 7;
  int tid  = threadIdx.x;

  for (int u = tid; u < 991; u += 512) {
    int p = (u < 15) ? (u - 15 + 29791) : (u - 15);
    lut[u] = table[p * 4 + head] * SL;
  }

  int w    = tid >> 6;
  int lane = tid & 63;
  int qrow = lane & 15;
  int g    = lane >> 4;
  int i    = qg * 128 + w * 16 + qrow;       // query index for m/l bookkeeping
  int iz = i >> 8, iy = (i >> 4) & 15, ix = i & 15;
  int lanebase = iz * 31 + iy + ix;
  int gof = ((g >= 2) ? 15 : 0) - 8 * g;     // permuted-key bias offset

  bf16x8 qf = *(const bf16x8*)(Qpk + ((size_t)(head << 12) + i) * 32 + g * 8);

  const unsigned short* Kh = Kb + (size_t)head * 4096 * 32;
  const unsigned short* Vh = Vt + (size_t)head * 32 * 4096;

  int kt0 = ksb * 16;                        // first 32-key tile of this slice

  // staging source (swizzled global addr, linear LDS dst = tid*8)
  const unsigned short* src;
  size_t sstride;
  if (tid < 256) {
    int key = tid >> 2, s = tid & 3;
    int gp  = s ^ ((key >> 1) & 3);
    src = Kh + (size_t)(kt0 * 32 + key) * 32 + gp * 8;
    sstride = 32 * 32;
  } else {
    int tt = tid - 256;
    int dh = tt >> 2, s = tt & 3;
    int gp = s ^ ((dh >> 1) & 3);
    src = Vh + (size_t)dh * 4096 + kt0 * 32 + gp * 8;
    sstride = 32;
  }
  int t8 = tid * 8;

  int sw    = (qrow >> 1) & 3;
  int k0off = qrow * 32 + ((g ^ sw) * 8);
  int k1off = k0off + 512;
  int v0off = 2048 + k0off;
  int v1off = v0off + 512;

  {
    bf16x8 s0 = *(const bf16x8*)src; src += sstride;
    *(bf16x8*)(&kvs[0][t8]) = s0;
  }
  __syncthreads();

  f32x4 zero = {0.f, 0.f, 0.f, 0.f};
  f32x4 accO0 = zero, accO1 = zero;
  float m2 = -1e30f, lpart = 0.f;
  int cur = 0;

  for (int ktl = 0; ktl < 16; ktl++) {
    int kt = kt0 + ktl;
    bf16x8 stg;
    if (ktl < 15) { stg = *(const bf16x8*)src; src += sstride; }

    bf16x8 kf0 = *(const bf16x8*)(&kvs[cur][k0off]);
    bf16x8 kf1 = *(const bf16x8*)(&kvs[cur][k1off]);
    bf16x8 vf0 = *(const bf16x8*)(&kvs[cur][v0off]);
    bf16x8 vf1 = *(const bf16x8*)(&kvs[cur][v1off]);

    f32x4 accA = __builtin_amdgcn_mfma_f32_16x16x32_bf16(kf0, qf, zero, 0, 0, 0);
    f32x4 accB = __builtin_amdgcn_mfma_f32_16x16x32_bf16(kf1, qf, zero, 0, 0, 0);

    // bias for permuted keys: accA[r] = key g*8+r, accB[r] = key g*8+4+r
    int z0 = kt >> 3, y0 = (kt << 1) & 15;
    int Cc = 495 - 31 * z0 - y0;
    const float* lp = &lut[lanebase + Cc + gof - 7];
    float b0 = lp[0], b1 = lp[1], b2 = lp[2], b3 = lp[3];
    float b4 = lp[4], b5 = lp[5], b6 = lp[6], b7 = lp[7];

    float t0 = fmaf(accA[0], SL, b7);
    float t1 = fmaf(accA[1], SL, b6);
    float t2 = fmaf(accA[2], SL, b5);
    float t3 = fmaf(accA[3], SL, b4);
    float t4 = fmaf(accB[0], SL, b3);
    float t5 = fmaf(accB[1], SL, b2);
    float t6 = fmaf(accB[2], SL, b1);
    float t7 = fmaf(accB[3], SL, b0);

    float cm = fmaxf(fmaxf(fmaxf(t0, t1), fmaxf(t2, t3)),
                     fmaxf(fmaxf(t4, t5), fmaxf(t6, t7)));
    cm = fmaxf(cm, __shfl_xor(cm, 16, 64));
    cm = fmaxf(cm, __shfl_xor(cm, 32, 64));

    if (__any(cm > m2 + 8.f)) {
      float mn   = fmaxf(m2, cm);
      float corr = exp2f(m2 - mn);          // per-row q = qrow
      m2 = mn;
      lpart *= corr;
      // accO regs hold q = g*4+r -> fetch that row's corr
      float c0 = __shfl(corr, g * 4 + 0, 64);
      float c1 = __shfl(corr, g * 4 + 1, 64);
      float c2 = __shfl(corr, g * 4 + 2, 64);
      float c3 = __shfl(corr, g * 4 + 3, 64);
      accO0[0] *= c0; accO0[1] *= c1; accO0[2] *= c2; accO0[3] *= c3;
      accO1[0] *= c0; accO1[1] *= c1; accO1[2] *= c2; accO1[3] *= c3;
    }

    float p0 = exp2f(t0 - m2), p1 = exp2f(t1 - m2);
    float p2 = exp2f(t2 - m2), p3 = exp2f(t3 - m2);
    float p4 = exp2f(t4 - m2), p5 = exp2f(t5 - m2);
    float p6 = exp2f(t6 - m2), p7 = exp2f(t7 - m2);
    lpart += ((p0 + p1) + (p2 + p3)) + ((p4 + p5) + (p6 + p7));

    // P A-frag: lane's own 8 keys (g*8+0..7), already in register
    union { i32x4 i4; bf16x8 s8; } pa;
    pa.i4 = (i32x4){ cvtpk(p0, p1), cvtpk(p2, p3),
                     cvtpk(p4, p5), cvtpk(p6, p7) };

    accO0 = __builtin_amdgcn_mfma_f32_16x16x32_bf16(pa.s8, vf0, accO0, 0, 0, 0);
    accO1 = __builtin_amdgcn_mfma_f32_16x16x32_bf16(pa.s8, vf1, accO1, 0, 0, 0);

    if (ktl < 15) *(bf16x8*)(&kvs[cur ^ 1][t8]) = stg;
    __syncthreads();
    cur ^= 1;
  }

  float lsum = lpart + __shfl_xor(lpart, 16, 64);
  lsum += __shfl_xor(lsum, 32, 64);

  // partial write: accO0[r] = O[q = g*4+r][d = qrow], accO1 -> d = 16+qrow
  int base = head * 8 + ksb;
  if (g == 0) {
    part_m[base * 4096 + i] = m2;
    part_l[base * 4096 + i] = lsum;
  }
  int i0 = qg * 128 + w * 16 + g * 4;        // 4-aligned query base
  *(f32x4*)&part_o[(size_t)(base * 32 + qrow) * 4096 + i0]      = accO0;
  *(f32x4*)&part_o[(size_t)(base * 32 + 16 + qrow) * 4096 + i0] = accO1;
}

// ---- K4b: combine the 8 key-slice partials, write channel-spatial ---------
__global__ __launch_bounds__(256) void attn_reduce_kernel(
    const float* __restrict__ part_o, const float* __restrict__ part_m,
    const float* __restrict__ part_l, float* __restrict__ o_sp) {
  int t = blockIdx.x * 256 + threadIdx.x;  // 16384
  int i = t & 4095, head = t >> 12;
  float mk[8], mx = -1e30f;
  #pragma unroll
  for (int ks = 0; ks < 8; ks++) { mk[ks] = part_m[(head*8+ks)*4096 + i]; mx = fmaxf(mx, mk[ks]); }
  float c[8], L = 0.f;
  #pragma unroll
  for (int ks = 0; ks < 8; ks++) {
    c[ks] = exp2f(mk[ks] - mx);
    L = fmaf(c[ks], part_l[(head*8+ks)*4096 + i], L);
  }
  float invL = 1.f / L;
  #pragma unroll
  for (int d = 0; d < 32; d++) {
    float acc = 0.f;
    #pragma unroll
    for (int ks = 0; ks < 8; ks++)
      acc = fmaf(c[ks], part_o[(size_t)((head*8+ks)*32 + d) * 4096 + i], acc);
    o_sp[(size_t)(d * 4 + head) * 4096 + i] = acc * invL;
  }
}

// ---- K5: depthwise out projection ----------------------------------------
__global__ __launch_bounds__(256) void dw_out_kernel(
    const float* __restrict__ in, const float* __restrict__ w, float* __restrict__ out) {
  dw_body<false>(in, w, nullptr, out, 16, 256, 4096, 128, blockIdx.x * 256 + threadIdx.x);
}

// ---- K6: pw_out 128->128 + r16 residue + deterministic BN partial sums ----
__global__ __launch_bounds__(256) void pw_out_kernel(
    const float* __restrict__ in, const float* __restrict__ w,
    const float* __restrict__ r16, float* __restrict__ res2,
    float* __restrict__ sums) {
  __shared__ float red[4][2][2];
  int oc0 = (blockIdx.x >> 3) * 2;
  int sb  = blockIdx.x & 7;
  int s0  = (sb * 256 + threadIdx.x) * 2;
  float a00 = 0.f, a01 = 0.f, a10 = 0.f, a11 = 0.f;
  const float* w0 = w + (size_t)oc0 * 128;
  const float* w1 = w0 + 128;
  #pragma unroll 8
  for (int ic = 0; ic < 128; ic++) {
    float xa = in[(size_t)ic * 4096 + s0];
    float xb = in[(size_t)ic * 4096 + s0 + 1];
    float wv0 = w0[ic], wv1 = w1[ic];
    a00 = fmaf(wv0, xa, a00); a01 = fmaf(wv0, xb, a01);
    a10 = fmaf(wv1, xa, a10); a11 = fmaf(wv1, xb, a11);
  }
  size_t ob0 = (size_t)oc0 * 4096 + s0;
  size_t ob1 = ob0 + 4096;
  float r00 = a00 + r16[ob0],     r01 = a01 + r16[ob0 + 1];
  float r10 = a10 + r16[ob1],     r11 = a11 + r16[ob1 + 1];
  res2[ob0] = r00; res2[ob0 + 1] = r01;
  res2[ob1] = r10; res2[ob1 + 1] = r11;
  float s_0 = r00 + r01, q_0 = fmaf(r00, r00, r01 * r01);
  float s_1 = r10 + r11, q_1 = fmaf(r10, r10, r11 * r11);
  #pragma unroll
  for (int off = 32; off; off >>= 1) {
    s_0 += __shfl_down(s_0, off, 64); q_0 += __shfl_down(q_0, off, 64);
    s_1 += __shfl_down(s_1, off, 64); q_1 += __shfl_down(q_1, off, 64);
  }
  int wid = threadIdx.x >> 6;
  if ((threadIdx.x & 63) == 0) {
    red[wid][0][0] = s_0; red[wid][0][1] = q_0;
    red[wid][1][0] = s_1; red[wid][1][1] = q_1;
  }
  __syncthreads();
  if (threadIdx.x < 2) {
    int o = threadIdx.x;
    float st = red[0][o][0] + red[1][o][0] + red[2][o][0] + red[3][o][0];
    float qt = red[0][o][1] + red[1][o][1] + red[2][o][1] + red[3][o][1];
    sums[(oc0 + o) * 8 + sb]        = st;
    sums[1024 + (oc0 + o) * 8 + sb] = qt;
  }
}

// ---- K7: mlp pw with in-block BN-affine finalize + ReLU + residual --------
__global__ __launch_bounds__(256) void pw_mlp_kernel(
    const float* __restrict__ res2, const float* __restrict__ w,
    const float* __restrict__ gamma2, const float* __restrict__ beta2,
    const float* __restrict__ sums, float* __restrict__ out) {
  __shared__ float A[128], Bb[128];
  if (threadIdx.x < 128) {
    int c = threadIdx.x;
    float s = 0.f, q = 0.f;
    #pragma unroll
    for (int sb = 0; sb < 8; sb++) { s += sums[c * 8 + sb]; q += sums[1024 + c * 8 + sb]; }
    float m   = s * (1.0f / 4096.0f);
    float var = q * (1.0f / 4096.0f) - m * m;
    float a   = gamma2[c] * rsqrtf(var + 1e-5f);
    A[c]  = a;
    Bb[c] = beta2[c] - m * a;
  }
  __syncthreads();
  int oc0 = (blockIdx.x >> 3) * 2;
  int sb  = blockIdx.x & 7;
  int s0  = (sb * 256 + threadIdx.x) * 2;
  float a00 = 0.f, a01 = 0.f, a10 = 0.f, a11 = 0.f;
  const float* w0 = w + (size_t)oc0 * 128;
  const float* w1 = w0 + 128;
  #pragma unroll 8
  for (int ic = 0; ic < 128; ic++) {
    float aa = A[ic], bb = Bb[ic];
    float xa = fmaxf(fmaf(res2[(size_t)ic * 4096 + s0], aa, bb), 0.f);
    float xb = fmaxf(fmaf(res2[(size_t)ic * 4096 + s0 + 1], aa, bb), 0.f);
    float wv0 = w0[ic], wv1 = w1[ic];
    a00 = fmaf(wv0, xa, a00); a01 = fmaf(wv0, xb, a01);
    a10 = fmaf(wv1, xa, a10); a11 = fmaf(wv1, xb, a11);
  }
  size_t ob0 = (size_t)oc0 * 4096 + s0;
  size_t ob1 = ob0 + 4096;
  out[ob0]     = a00 + res2[ob0];
  out[ob0 + 1] = a01 + res2[ob0 + 1];
  out[ob1]     = a10 + res2[ob1];
  out[ob1 + 1] = a11 + res2[ob1 + 1];
}

// ---------------------------------------------------------------------------
extern "C" void kernel_launch(void* const* d_in, const int* in_sizes, int n_in,
                              void* d_out, int out_size, void* d_ws, size_t ws_size,
                              hipStream_t stream) {
  (void)in_sizes; (void)n_in; (void)out_size; (void)ws_size;
  const float* x1      = (const float*)d_in[0];
  const float* x2      = (const float*)d_in[1];
  const float* w_ch    = (const float*)d_in[2];
  const float* b_ch    = (const float*)d_in[3];
  const float* gamma_l = (const float*)d_in[4];
  const float* beta_l  = (const float*)d_in[5];
  const float* gamma_h = (const float*)d_in[6];
  const float* beta_h  = (const float*)d_in[7];
  const float* gamma2  = (const float*)d_in[8];
  const float* beta2   = (const float*)d_in[9];
  const float* kv_dw   = (const float*)d_in[10];
  const float* kv_pw   = (const float*)d_in[11];
  const float* q_dw    = (const float*)d_in[12];
  const float* q_pw    = (const float*)d_in[13];
  const float* out_dw  = (const float*)d_in[14];
  const float* out_pw  = (const float*)d_in[15];
  const float* w_mlp   = (const float*)d_in[16];
  const float* rtab    = (const float*)d_in[17];

  float* ws = (float*)d_ws;
  float* ab_l = ws + 0;        //    512
  float* ab_h = ws + 512;      //    256
  float* sums = ws + 768;      //   2048
  float* res8 = ws + 2816;     //  65536
  float* kvdw = ws + 68352;    // 131072
  float* qdw  = ws + 199424;   // 524288 -> 723712
  unsigned short* Qpk = (unsigned short*)(ws + 723712);   // 262144 f -> 985856
  unsigned short* Kb  = (unsigned short*)(ws + 985856);   // 262144 f -> 1248000
  unsigned short* Vt  = (unsigned short*)(ws + 1248000);  // 262144 f -> 1510144
  float* r16  = ws + 1510144;  // 524288 -> 2034432
  float* o_sp = ws + 2034432;  // 524288 -> 2558720
  float* odw  = ws + 2558720;  // 524288 -> 3083008
  float* res2 = ws + 3083008;  // 524288 -> 3607296
  float* part_o = ws + 3607296; // 4194304 -> 7801600
  float* part_m = ws + 7801600; // 131072  -> 7932672
  float* part_l = ws + 7932672; // 131072  -> 8063744 floats (~32.3 MB)

  bnstat_both_kernel<<<384, 256, 0, stream>>>(x1, x2, gamma_l, beta_l, gamma_h, beta_h,
                                              ab_l, ab_h);
  stageA_kernel<<<2688, 256, 0, stream>>>(x1, x2, w_ch, b_ch, kv_dw, q_dw,
                                          ab_l, ab_h, res8, kvdw, qdw);
  stageB_kernel<<<1280, 512, 0, stream>>>(kvdw, kv_pw, qdw, q_pw, res8,
                                          Kb, Vt, Qpk, r16);
  attn_mfma_kernel<<<1024, 512, 0, stream>>>(Qpk, Kb, Vt, rtab,
                                             part_o, part_m, part_l);
  attn_reduce_kernel<<<64, 256, 0, stream>>>(part_o, part_m, part_l, o_sp);
  dw_out_kernel<<<2048, 256, 0, stream>>>(o_sp, out_dw, odw);
  pw_out_kernel<<<512, 256, 0, stream>>>(odw, out_pw, r16, res2, sums);
  pw_mlp_kernel<<<512, 256, 0, stream>>>(res2, w_mlp, gamma2, beta2, sums, (float*)d_out);
}